// Round 1
// baseline (4014.720 us; speedup 1.0000x reference)
//
#include <hip/hip_runtime.h>

#define B_ 4
#define L_ 2048
#define D_ 512
#define S_ 256
#define H_ 8
#define DH_ 64
#define WIN_ 256
#define EPS_ 1e-5f

using f32x4 = __attribute__((ext_vector_type(4))) float;
using s16x8 = __attribute__((ext_vector_type(8))) short;

__device__ __forceinline__ unsigned short f2b(float f) {
  unsigned int u = __builtin_bit_cast(unsigned int, f);
  u += 0x7FFFu + ((u >> 16) & 1u);   // RNE to bf16 (inputs finite)
  return (unsigned short)(u >> 16);
}

// ---------- f32 -> bf16 convert (n4 = n/4) ----------
__global__ __launch_bounds__(256) void k_f2b(const float* __restrict__ in,
                                             unsigned short* __restrict__ out, int n4) {
  int i = blockIdx.x * 256 + threadIdx.x;
  if (i >= n4) return;
  float4 v = reinterpret_cast<const float4*>(in)[i];
  ushort4 o;
  o.x = f2b(v.x); o.y = f2b(v.y); o.z = f2b(v.z); o.w = f2b(v.w);
  reinterpret_cast<ushort4*>(out)[i] = o;
}

// ---------- transpose+convert Wx (NL,D,S) -> (NL,S,D) bf16 ----------
__global__ void k_twx(const float* __restrict__ wx, unsigned short* __restrict__ wxt) {
  __shared__ float tile[32][33];
  int lyr = blockIdx.z;
  int d0 = blockIdx.x * 32, s0 = blockIdx.y * 32;
  const float* src = wx + (size_t)lyr * D_ * S_;
  unsigned short* dst = wxt + (size_t)lyr * S_ * D_;
  for (int r = threadIdx.y; r < 32; r += 8)
    tile[r][threadIdx.x] = src[(size_t)(d0 + r) * S_ + s0 + threadIdx.x];
  __syncthreads();
  for (int r = threadIdx.y; r < 32; r += 8)
    dst[(size_t)(s0 + r) * D_ + d0 + threadIdx.x] = f2b(tile[threadIdx.x][r]);
}

// ---------- causal depthwise conv (k=3) + SiLU, write bf16 ----------
__global__ __launch_bounds__(128) void k_conv_silu(const float* __restrict__ seq,
                                                   const float* __restrict__ cw,
                                                   unsigned short* __restrict__ x) {
  int bl = blockIdx.x;
  int l = bl & (L_ - 1);
  int t = threadIdx.x;
  const float4* s4 = reinterpret_cast<const float4*>(seq);
  const float4* c4 = reinterpret_cast<const float4*>(cw);
  size_t row = (size_t)bl * 128;
  float4 c0 = c4[t], c1 = c4[128 + t], c2 = c4[256 + t];
  float4 z = make_float4(0.f, 0.f, 0.f, 0.f);
  float4 s0 = (l >= 2) ? s4[row - 256 + t] : z;
  float4 s1 = (l >= 1) ? s4[row - 128 + t] : z;
  float4 s2 = s4[row + t];
  float y0 = c0.x * s0.x + c1.x * s1.x + c2.x * s2.x;
  float y1 = c0.y * s0.y + c1.y * s1.y + c2.y * s2.y;
  float y2 = c0.z * s0.z + c1.z * s1.z + c2.z * s2.z;
  float y3 = c0.w * s0.w + c1.w * s1.w + c2.w * s2.w;
  float v0 = y0 / (1.f + expf(-y0));
  float v1 = y1 / (1.f + expf(-y1));
  float v2 = y2 / (1.f + expf(-y2));
  float v3 = y3 / (1.f + expf(-y3));
  ushort4 o;
  o.x = f2b(v0); o.y = f2b(v1); o.z = f2b(v2); o.w = f2b(v3);
  reinterpret_cast<ushort4*>(x)[row + t] = o;
}

// ---------- h0 = state @ Wh ----------
__global__ __launch_bounds__(256) void k_h0(const float* __restrict__ state,
                                            const float* __restrict__ Wh,
                                            float* __restrict__ h0) {
  int b = blockIdx.x, s = threadIdx.x;
  float acc = 0.f;
  for (int d = 0; d < D_; ++d) acc += state[b * D_ + d] * Wh[(size_t)d * S_ + s];
  h0[b * S_ + s] = acc;
}

// ---------- bf16 MFMA GEMM: C[M,N] = A[M,K] * Bt[N,K]^T (+bias) ----------
__global__ __launch_bounds__(256) void k_gemm(const unsigned short* __restrict__ A,
                                              const unsigned short* __restrict__ Bt,
                                              float* __restrict__ C,
                                              const float* __restrict__ bias,
                                              int M, int N, int K) {
  __shared__ __align__(16) unsigned short As[64][40];
  __shared__ __align__(16) unsigned short Bs[64][40];
  int m0 = blockIdx.x * 64, n0 = blockIdx.y * 64;
  int t = threadIdx.x;
  int lane = t & 63, wid = t >> 6;
  int wr = wid >> 1, wc = wid & 1;
  int g = lane >> 4, mr = lane & 15;
  int sr = t >> 2, sc = (t & 3) * 8;
  f32x4 acc[2][2];
#pragma unroll
  for (int i_ = 0; i_ < 2; ++i_)
#pragma unroll
    for (int j_ = 0; j_ < 2; ++j_) {
      f32x4 zz = {0.f, 0.f, 0.f, 0.f};
      acc[i_][j_] = zz;
    }
  const unsigned short* ag = A + (size_t)(m0 + sr) * K + sc;
  const unsigned short* bg = Bt + (size_t)(n0 + sr) * K + sc;
  for (int k0 = 0; k0 < K; k0 += 32) {
    s16x8 av = *reinterpret_cast<const s16x8*>(ag + k0);
    s16x8 bv = *reinterpret_cast<const s16x8*>(bg + k0);
    __syncthreads();
    *reinterpret_cast<s16x8*>(&As[sr][sc]) = av;
    *reinterpret_cast<s16x8*>(&Bs[sr][sc]) = bv;
    __syncthreads();
    s16x8 a0 = *reinterpret_cast<const s16x8*>(&As[wr * 32 + mr][g * 8]);
    s16x8 a1 = *reinterpret_cast<const s16x8*>(&As[wr * 32 + 16 + mr][g * 8]);
    s16x8 b0 = *reinterpret_cast<const s16x8*>(&Bs[wc * 32 + mr][g * 8]);
    s16x8 b1 = *reinterpret_cast<const s16x8*>(&Bs[wc * 32 + 16 + mr][g * 8]);
    acc[0][0] = __builtin_amdgcn_mfma_f32_16x16x32_bf16(a0, b0, acc[0][0], 0, 0, 0);
    acc[0][1] = __builtin_amdgcn_mfma_f32_16x16x32_bf16(a0, b1, acc[0][1], 0, 0, 0);
    acc[1][0] = __builtin_amdgcn_mfma_f32_16x16x32_bf16(a1, b0, acc[1][0], 0, 0, 0);
    acc[1][1] = __builtin_amdgcn_mfma_f32_16x16x32_bf16(a1, b1, acc[1][1], 0, 0, 0);
  }
#pragma unroll
  for (int fm = 0; fm < 2; ++fm) {
#pragma unroll
    for (int fn = 0; fn < 2; ++fn) {
      int row = m0 + wr * 32 + fm * 16 + g * 4;
      int col = n0 + wc * 32 + fn * 16 + mr;
      float badd = bias ? bias[col] : 0.f;
#pragma unroll
      for (int q = 0; q < 4; ++q)
        C[(size_t)(row + q) * N + col] = acc[fm][fn][q] + badd;
    }
  }
}

// ---------- weighted reduce of u over l-chunks: part[b][c][s] ----------
__global__ __launch_bounds__(256) void k_ured(const float* __restrict__ u,
                                              const float* __restrict__ Ap,
                                              float* __restrict__ part) {
  int c = blockIdx.x, b = blockIdx.y, s = threadIdx.x;
  float a = 1.f / (1.f + expf(-Ap[s]));
  float la = logf(a);
  float acc = 0.f;
  const float* up = u + (size_t)(b * L_ + c * 128) * S_ + s;
  int base = c * 128;
  for (int j = 0; j < 128; ++j) {
    float p = (float)(L_ - 1 - (base + j));
    acc += up[(size_t)j * S_] * expf(p * la);
  }
  part[(size_t)(b * 16 + c) * S_ + s] = acc;
}

// ---------- hT = a^L * h0 + sum_c part ----------
__global__ __launch_bounds__(256) void k_hT(const float* __restrict__ part,
                                            const float* __restrict__ h0,
                                            const float* __restrict__ Ap,
                                            float* __restrict__ hT, int hash0) {
  int b = blockIdx.x, s = threadIdx.x;
  float acc = 0.f;
  for (int c = 0; c < 16; ++c) acc += part[(size_t)(b * 16 + c) * S_ + s];
  if (hash0) {
    float a = 1.f / (1.f + expf(-Ap[s]));
    acc += expf(2048.f * logf(a)) * h0[b * S_ + s];
  }
  hT[b * S_ + s] = acc;
}

// ---------- state = hT @ Wout ----------
__global__ __launch_bounds__(256) void k_state(const float* __restrict__ hT,
                                               const float* __restrict__ Wout,
                                               float* __restrict__ state) {
  int b = blockIdx.x, t = threadIdx.x;
#pragma unroll
  for (int r = 0; r < 2; ++r) {
    int d = r * 256 + t;
    float acc = 0.f;
    for (int s = 0; s < S_; ++s) acc += hT[b * S_ + s] * Wout[(size_t)s * D_ + d];
    state[b * D_ + d] = acc;
  }
}

// ---------- LayerNorm(seq + add), in place; add is (B,D) or (B,L,D) ----------
__global__ __launch_bounds__(128) void k_ln(float* __restrict__ seq,
                                            const float* __restrict__ add, int addfull,
                                            const float* __restrict__ gamma,
                                            const float* __restrict__ beta) {
  int bl = blockIdx.x;
  int b = bl >> 11;
  int t = threadIdx.x;
  float4 v = reinterpret_cast<float4*>(seq)[(size_t)bl * 128 + t];
  const float4* a4 = reinterpret_cast<const float4*>(add);
  float4 a = addfull ? a4[(size_t)bl * 128 + t] : a4[b * 128 + t];
  v.x += a.x; v.y += a.y; v.z += a.z; v.w += a.w;
  float s = v.x + v.y + v.z + v.w;
  float s2 = v.x * v.x + v.y * v.y + v.z * v.z + v.w * v.w;
#pragma unroll
  for (int off = 32; off >= 1; off >>= 1) {
    s += __shfl_down(s, off);
    s2 += __shfl_down(s2, off);
  }
  __shared__ float r1[2], r2[2];
  if ((t & 63) == 0) { r1[t >> 6] = s; r2[t >> 6] = s2; }
  __syncthreads();
  float fs = r1[0] + r1[1], fq = r2[0] + r2[1];
  float mu = fs * (1.f / D_);
  float var = fq * (1.f / D_) - mu * mu;
  float rstd = rsqrtf(var + EPS_);
  float4 g = reinterpret_cast<const float4*>(gamma)[t];
  float4 be = reinterpret_cast<const float4*>(beta)[t];
  float4 o;
  o.x = (v.x - mu) * rstd * g.x + be.x;
  o.y = (v.y - mu) * rstd * g.y + be.y;
  o.z = (v.z - mu) * rstd * g.z + be.z;
  o.w = (v.w - mu) * rstd * g.w + be.w;
  reinterpret_cast<float4*>(seq)[(size_t)bl * 128 + t] = o;
}

// ---------- banded attention core: qkv(f32) -> attn out (bf16) ----------
__global__ __launch_bounds__(256) void k_attn(const float* __restrict__ qkv,
                                              unsigned short* __restrict__ attnbf) {
  int b = blockIdx.z, h = blockIdx.y, q0 = blockIdx.x * 16;
  int t = threadIdx.x;
  int lane = t & 63, wid = t >> 6;
  __shared__ float q_sm[64];
  __shared__ float sc_sm[528];
  __shared__ float red_sm[4];
  __shared__ float red2_sm[4];
  __shared__ float out_sm[4][64];
  int kstart = q0 - WIN_; if (kstart < 0) kstart = 0;
  int kend = q0 + 15 + WIN_ + 1; if (kend > L_) kend = L_;
  int nk = kend - kstart;
  for (int qi = 0; qi < 16; ++qi) {
    int q = q0 + qi;
    __syncthreads();
    if (t < 64) q_sm[t] = qkv[(size_t)(b * L_ + q) * 1536 + h * 64 + t];
    __syncthreads();
    float lmax = -1e30f;
    for (int kk = t; kk < nk; kk += 256) {
      int k = kstart + kk;
      int dd = k - q; if (dd < 0) dd = -dd;
      float sv = -1e30f;
      if (dd <= WIN_) {
        const float* kv = qkv + (size_t)(b * L_ + k) * 1536 + 512 + h * 64;
        float acc = 0.f;
#pragma unroll
        for (int d = 0; d < 64; ++d) acc += q_sm[d] * kv[d];
        sv = acc * 0.125f;
      }
      sc_sm[kk] = sv;
      lmax = fmaxf(lmax, sv);
    }
#pragma unroll
    for (int off = 32; off >= 1; off >>= 1) lmax = fmaxf(lmax, __shfl_down(lmax, off));
    if (lane == 0) red_sm[wid] = lmax;
    __syncthreads();
    float gmax = fmaxf(fmaxf(red_sm[0], red_sm[1]), fmaxf(red_sm[2], red_sm[3]));
    float lsum = 0.f;
    for (int kk = t; kk < nk; kk += 256) {
      float p = expf(sc_sm[kk] - gmax);
      sc_sm[kk] = p;
      lsum += p;
    }
#pragma unroll
    for (int off = 32; off >= 1; off >>= 1) lsum += __shfl_down(lsum, off);
    if (lane == 0) red2_sm[wid] = lsum;
    __syncthreads();
    float inv = 1.f / (red2_sm[0] + red2_sm[1] + red2_sm[2] + red2_sm[3]);
    int d = t & 63, sl = t >> 6;
    float acc = 0.f;
    for (int kk = sl; kk < nk; kk += 4)
      acc += sc_sm[kk] * qkv[(size_t)(b * L_ + kstart + kk) * 1536 + 1024 + h * 64 + d];
    out_sm[sl][d] = acc;
    __syncthreads();
    if (t < 64) {
      float o = (out_sm[0][t] + out_sm[1][t] + out_sm[2][t] + out_sm[3][t]) * inv;
      attnbf[(size_t)(b * L_ + q) * 512 + h * 64 + t] = f2b(o);
    }
  }
}

extern "C" void kernel_launch(void* const* d_in, const int* in_sizes, int n_in,
                              void* d_out, int out_size, void* d_ws, size_t ws_size,
                              hipStream_t stream) {
  const float* context = (const float*)d_in[0];
  const float* conv_w  = (const float*)d_in[1];
  const float* Wx      = (const float*)d_in[2];
  const float* Wh      = (const float*)d_in[3];
  const float* Wout    = (const float*)d_in[4];
  const float* Aparm   = (const float*)d_in[5];
  const float* gamma_m = (const float*)d_in[6];
  const float* beta_m  = (const float*)d_in[7];
  const float* gamma_a = (const float*)d_in[8];
  const float* beta_a  = (const float*)d_in[9];
  const float* Wqkv    = (const float*)d_in[10];
  const float* bqkv    = (const float*)d_in[11];
  const float* Wo      = (const float*)d_in[12];
  const float* bo      = (const float*)d_in[13];
  float* seq = (float*)d_out;
  float* ws = (float*)d_ws;

  // ws layout (floats). qkv region is aliased by u (mamba phases) and proj
  // (post-attention) -- temporally disjoint uses, stream-ordered.
  float* qkv  = ws;                                   // 12,582,912
  float* u    = ws;                                   //  2,097,152 (alias)
  float* proj = ws + 4194304;                         //  4,194,304 (alias)
  unsigned short* xbf    = (unsigned short*)(ws + 12582912);
  unsigned short* attnbf = (unsigned short*)(ws + 12582912 + 2097152);
  unsigned short* seqbf  = (unsigned short*)(ws + 12582912 + 2 * 2097152);
  unsigned short* wqkvbf = (unsigned short*)(ws + 12582912 + 3 * 2097152);
  unsigned short* wobf   = (unsigned short*)(ws + 12582912 + 3 * 2097152 + 393216);
  unsigned short* wxtbf  = (unsigned short*)(ws + 12582912 + 3 * 2097152 + 393216 + 131072);
  float* state = ws + 12582912 + 3 * 2097152 + 393216 + 131072 + 393216;
  float* h0    = state + 2048;
  float* hT    = h0 + 1024;
  float* part  = hT + 1024;

  hipMemcpyAsync(seq, context, (size_t)B_ * L_ * D_ * 4, hipMemcpyDeviceToDevice, stream);
  k_f2b<<<768, 256, 0, stream>>>(Wqkv, wqkvbf, 196608);
  k_f2b<<<256, 256, 0, stream>>>(Wo, wobf, 65536);
  k_twx<<<dim3(16, 8, 6), dim3(32, 8), 0, stream>>>(Wx, wxtbf);

  for (int i = 0; i < 6; ++i) {
    k_conv_silu<<<B_ * L_, 128, 0, stream>>>(seq, conv_w + (size_t)i * 3 * D_, xbf);
    if (i > 0) k_h0<<<B_, 256, 0, stream>>>(state, Wh + (size_t)i * D_ * S_, h0);
    k_gemm<<<dim3(128, 4), 256, 0, stream>>>(xbf, wxtbf + (size_t)i * S_ * D_, u, nullptr, 8192, 256, 512);
    k_ured<<<dim3(16, 4), 256, 0, stream>>>(u, Aparm + (size_t)i * S_, part);
    k_hT<<<B_, 256, 0, stream>>>(part, h0, Aparm + (size_t)i * S_, hT, i > 0 ? 1 : 0);
    k_state<<<B_, 256, 0, stream>>>(hT, Wout + (size_t)i * S_ * D_, state);
    k_ln<<<B_ * L_, 128, 0, stream>>>(seq, state, 0, gamma_m, beta_m);
    if (i == 3) {
      k_f2b<<<4096, 256, 0, stream>>>(seq, seqbf, 1048576);
      k_gemm<<<dim3(128, 24), 256, 0, stream>>>(seqbf, wqkvbf, qkv, bqkv, 8192, 1536, 512);
      k_attn<<<dim3(128, 8, 4), 256, 0, stream>>>(qkv, attnbf);
      k_gemm<<<dim3(128, 8), 256, 0, stream>>>(attnbf, wobf, proj, bo, 8192, 512, 512);
      k_ln<<<B_ * L_, 128, 0, stream>>>(seq, proj, 1, gamma_a, beta_a);
    }
  }
}

// Round 2
// 608.982 us; speedup vs baseline: 6.5925x; 6.5925x over previous
//
#include <hip/hip_runtime.h>

#define B_ 4
#define L_ 2048
#define D_ 512
#define S_ 256
#define H_ 8
#define DH_ 64
#define WIN_ 256
#define EPS_ 1e-5f
#define LOG2E_ 1.4426950408889634f

using f32x4 = __attribute__((ext_vector_type(4))) float;
using s16x8 = __attribute__((ext_vector_type(8))) short;

__device__ __forceinline__ unsigned short f2b(float f) {
  unsigned int u = __builtin_bit_cast(unsigned int, f);
  u += 0x7FFFu + ((u >> 16) & 1u);   // RNE to bf16 (inputs finite)
  return (unsigned short)(u >> 16);
}

// ---------- f32 -> bf16 convert (n4 = n/4) ----------
__global__ __launch_bounds__(256) void k_f2b(const float* __restrict__ in,
                                             unsigned short* __restrict__ out, int n4) {
  int i = blockIdx.x * 256 + threadIdx.x;
  if (i >= n4) return;
  float4 v = reinterpret_cast<const float4*>(in)[i];
  ushort4 o;
  o.x = f2b(v.x); o.y = f2b(v.y); o.z = f2b(v.z); o.w = f2b(v.w);
  reinterpret_cast<ushort4*>(out)[i] = o;
}

// ---------- transpose+convert Wx (NL,D,S) -> (NL,S,D) bf16 ----------
__global__ void k_twx(const float* __restrict__ wx, unsigned short* __restrict__ wxt) {
  __shared__ float tile[32][33];
  int lyr = blockIdx.z;
  int d0 = blockIdx.x * 32, s0 = blockIdx.y * 32;
  const float* src = wx + (size_t)lyr * D_ * S_;
  unsigned short* dst = wxt + (size_t)lyr * S_ * D_;
  for (int r = threadIdx.y; r < 32; r += 8)
    tile[r][threadIdx.x] = src[(size_t)(d0 + r) * S_ + s0 + threadIdx.x];
  __syncthreads();
  for (int r = threadIdx.y; r < 32; r += 8)
    dst[(size_t)(s0 + r) * D_ + d0 + threadIdx.x] = f2b(tile[threadIdx.x][r]);
}

// ---------- causal depthwise conv (k=3) + SiLU, write bf16 ----------
__global__ __launch_bounds__(128) void k_conv_silu(const float* __restrict__ seq,
                                                   const float* __restrict__ cw,
                                                   unsigned short* __restrict__ x) {
  int bl = blockIdx.x;
  int l = bl & (L_ - 1);
  int t = threadIdx.x;
  const float4* s4 = reinterpret_cast<const float4*>(seq);
  const float4* c4 = reinterpret_cast<const float4*>(cw);
  size_t row = (size_t)bl * 128;
  float4 c0 = c4[t], c1 = c4[128 + t], c2 = c4[256 + t];
  float4 z = make_float4(0.f, 0.f, 0.f, 0.f);
  float4 s0 = (l >= 2) ? s4[row - 256 + t] : z;
  float4 s1 = (l >= 1) ? s4[row - 128 + t] : z;
  float4 s2 = s4[row + t];
  float y0 = c0.x * s0.x + c1.x * s1.x + c2.x * s2.x;
  float y1 = c0.y * s0.y + c1.y * s1.y + c2.y * s2.y;
  float y2 = c0.z * s0.z + c1.z * s1.z + c2.z * s2.z;
  float y3 = c0.w * s0.w + c1.w * s1.w + c2.w * s2.w;
  float v0 = y0 / (1.f + expf(-y0));
  float v1 = y1 / (1.f + expf(-y1));
  float v2 = y2 / (1.f + expf(-y2));
  float v3 = y3 / (1.f + expf(-y3));
  ushort4 o;
  o.x = f2b(v0); o.y = f2b(v1); o.z = f2b(v2); o.w = f2b(v3);
  reinterpret_cast<ushort4*>(x)[row + t] = o;
}

// ---------- h0 = state @ Wh ----------
__global__ __launch_bounds__(256) void k_h0(const float* __restrict__ state,
                                            const float* __restrict__ Wh,
                                            float* __restrict__ h0) {
  int b = blockIdx.x, s = threadIdx.x;
  float acc = 0.f;
  for (int d = 0; d < D_; ++d) acc += state[b * D_ + d] * Wh[(size_t)d * S_ + s];
  h0[b * S_ + s] = acc;
}

// ---------- bf16 MFMA GEMM: C[M,N] = A[M,K] * Bt[N,K]^T (+bias) ----------
__global__ __launch_bounds__(256) void k_gemm(const unsigned short* __restrict__ A,
                                              const unsigned short* __restrict__ Bt,
                                              float* __restrict__ C,
                                              const float* __restrict__ bias,
                                              int M, int N, int K) {
  __shared__ __align__(16) unsigned short As[64][40];
  __shared__ __align__(16) unsigned short Bs[64][40];
  int m0 = blockIdx.x * 64, n0 = blockIdx.y * 64;
  int t = threadIdx.x;
  int lane = t & 63, wid = t >> 6;
  int wr = wid >> 1, wc = wid & 1;
  int g = lane >> 4, mr = lane & 15;
  int sr = t >> 2, sc = (t & 3) * 8;
  f32x4 acc[2][2];
#pragma unroll
  for (int i_ = 0; i_ < 2; ++i_)
#pragma unroll
    for (int j_ = 0; j_ < 2; ++j_) {
      f32x4 zz = {0.f, 0.f, 0.f, 0.f};
      acc[i_][j_] = zz;
    }
  const unsigned short* ag = A + (size_t)(m0 + sr) * K + sc;
  const unsigned short* bg = Bt + (size_t)(n0 + sr) * K + sc;
  for (int k0 = 0; k0 < K; k0 += 32) {
    s16x8 av = *reinterpret_cast<const s16x8*>(ag + k0);
    s16x8 bv = *reinterpret_cast<const s16x8*>(bg + k0);
    __syncthreads();
    *reinterpret_cast<s16x8*>(&As[sr][sc]) = av;
    *reinterpret_cast<s16x8*>(&Bs[sr][sc]) = bv;
    __syncthreads();
    s16x8 a0 = *reinterpret_cast<const s16x8*>(&As[wr * 32 + mr][g * 8]);
    s16x8 a1 = *reinterpret_cast<const s16x8*>(&As[wr * 32 + 16 + mr][g * 8]);
    s16x8 b0 = *reinterpret_cast<const s16x8*>(&Bs[wc * 32 + mr][g * 8]);
    s16x8 b1 = *reinterpret_cast<const s16x8*>(&Bs[wc * 32 + 16 + mr][g * 8]);
    acc[0][0] = __builtin_amdgcn_mfma_f32_16x16x32_bf16(a0, b0, acc[0][0], 0, 0, 0);
    acc[0][1] = __builtin_amdgcn_mfma_f32_16x16x32_bf16(a0, b1, acc[0][1], 0, 0, 0);
    acc[1][0] = __builtin_amdgcn_mfma_f32_16x16x32_bf16(a1, b0, acc[1][0], 0, 0, 0);
    acc[1][1] = __builtin_amdgcn_mfma_f32_16x16x32_bf16(a1, b1, acc[1][1], 0, 0, 0);
  }
#pragma unroll
  for (int fm = 0; fm < 2; ++fm) {
#pragma unroll
    for (int fn = 0; fn < 2; ++fn) {
      int row = m0 + wr * 32 + fm * 16 + g * 4;
      int col = n0 + wc * 32 + fn * 16 + mr;
      float badd = bias ? bias[col] : 0.f;
#pragma unroll
      for (int q = 0; q < 4; ++q)
        C[(size_t)(row + q) * N + col] = acc[fm][fn][q] + badd;
    }
  }
}

// ---------- QKV GEMM with fused split epilogue: writes Qbf/Kbf/Vbf [B,H,L,64] bf16 ----------
__global__ __launch_bounds__(256) void k_gemm_qkv(const unsigned short* __restrict__ A,
                                                  const unsigned short* __restrict__ Bt,
                                                  const float* __restrict__ bias,
                                                  unsigned short* __restrict__ Qbf,
                                                  unsigned short* __restrict__ Kbf,
                                                  unsigned short* __restrict__ Vbf) {
  const int K = 512, M_ = 8192;
  (void)M_;
  __shared__ __align__(16) unsigned short As[64][40];
  __shared__ __align__(16) unsigned short Bs[64][40];
  int m0 = blockIdx.x * 64, n0 = blockIdx.y * 64;
  int t = threadIdx.x;
  int lane = t & 63, wid = t >> 6;
  int wr = wid >> 1, wc = wid & 1;
  int g = lane >> 4, mr = lane & 15;
  int sr = t >> 2, sc = (t & 3) * 8;
  f32x4 acc[2][2];
#pragma unroll
  for (int i_ = 0; i_ < 2; ++i_)
#pragma unroll
    for (int j_ = 0; j_ < 2; ++j_) {
      f32x4 zz = {0.f, 0.f, 0.f, 0.f};
      acc[i_][j_] = zz;
    }
  const unsigned short* ag = A + (size_t)(m0 + sr) * K + sc;
  const unsigned short* bg = Bt + (size_t)(n0 + sr) * K + sc;
  for (int k0 = 0; k0 < K; k0 += 32) {
    s16x8 av = *reinterpret_cast<const s16x8*>(ag + k0);
    s16x8 bv = *reinterpret_cast<const s16x8*>(bg + k0);
    __syncthreads();
    *reinterpret_cast<s16x8*>(&As[sr][sc]) = av;
    *reinterpret_cast<s16x8*>(&Bs[sr][sc]) = bv;
    __syncthreads();
    s16x8 a0 = *reinterpret_cast<const s16x8*>(&As[wr * 32 + mr][g * 8]);
    s16x8 a1 = *reinterpret_cast<const s16x8*>(&As[wr * 32 + 16 + mr][g * 8]);
    s16x8 b0 = *reinterpret_cast<const s16x8*>(&Bs[wc * 32 + mr][g * 8]);
    s16x8 b1 = *reinterpret_cast<const s16x8*>(&Bs[wc * 32 + 16 + mr][g * 8]);
    acc[0][0] = __builtin_amdgcn_mfma_f32_16x16x32_bf16(a0, b0, acc[0][0], 0, 0, 0);
    acc[0][1] = __builtin_amdgcn_mfma_f32_16x16x32_bf16(a0, b1, acc[0][1], 0, 0, 0);
    acc[1][0] = __builtin_amdgcn_mfma_f32_16x16x32_bf16(a1, b0, acc[1][0], 0, 0, 0);
    acc[1][1] = __builtin_amdgcn_mfma_f32_16x16x32_bf16(a1, b1, acc[1][1], 0, 0, 0);
  }
#pragma unroll
  for (int fm = 0; fm < 2; ++fm) {
#pragma unroll
    for (int fn = 0; fn < 2; ++fn) {
      int row0 = m0 + wr * 32 + fm * 16 + g * 4;
      int col = n0 + wc * 32 + fn * 16 + mr;
      int sec = col >> 9;           // 0=Q 1=K 2=V
      int hh = (col >> 6) & 7;
      int dh = col & 63;
      float badd = bias[col];
      float scale = (sec == 0) ? 0.125f : 1.f;
      unsigned short* dstbase = (sec == 0) ? Qbf : (sec == 1 ? Kbf : Vbf);
#pragma unroll
      for (int q = 0; q < 4; ++q) {
        int row = row0 + q;
        int b = row >> 11, l = row & 2047;
        dstbase[(((size_t)(b * H_ + hh)) * L_ + l) * 64 + dh] =
            f2b((acc[fm][fn][q] + badd) * scale);
      }
    }
  }
}

// ---------- flash banded attention: Q/K/V bf16 [B,H,L,64] -> attnbf [B,L,512] ----------
__global__ __launch_bounds__(256) void k_fattn(const unsigned short* __restrict__ Qbf,
                                               const unsigned short* __restrict__ Kbf,
                                               const unsigned short* __restrict__ Vbf,
                                               unsigned short* __restrict__ attnbf) {
  __shared__ __align__(16) unsigned short Ks[64][72];
  __shared__ __align__(16) unsigned short Vt[64][72];
  __shared__ __align__(16) unsigned short Ps[4][16][72];
  int b = blockIdx.z, h = blockIdx.y, q0 = blockIdx.x * 64;
  int t = threadIdx.x;
  int lane = t & 63, wid = t >> 6;
  int g = lane >> 4, mr = lane & 15;
  const unsigned short* Qp = Qbf + ((size_t)(b * H_ + h)) * L_ * 64;
  const unsigned short* Kp = Kbf + ((size_t)(b * H_ + h)) * L_ * 64;
  const unsigned short* Vp = Vbf + ((size_t)(b * H_ + h)) * L_ * 64;
  int qbase = q0 + wid * 16;
  // Q A-fragments (row = mr within wave's 16 queries, k = g*8+j [+32])
  s16x8 qf0 = *reinterpret_cast<const s16x8*>(Qp + (size_t)(qbase + mr) * 64 + g * 8);
  s16x8 qf1 = *reinterpret_cast<const s16x8*>(Qp + (size_t)(qbase + mr) * 64 + 32 + g * 8);
  f32x4 oacc[4];
#pragma unroll
  for (int fn = 0; fn < 4; ++fn) { f32x4 zz = {0.f,0.f,0.f,0.f}; oacc[fn] = zz; }
  float m_[4] = {-1e30f, -1e30f, -1e30f, -1e30f};
  float l_[4] = {0.f, 0.f, 0.f, 0.f};
  int kstart = q0 - WIN_; if (kstart < 0) kstart = 0;
  int kend = q0 + 64 + WIN_; if (kend > L_) kend = L_;

  for (int kt = kstart; kt < kend; kt += 64) {
    __syncthreads();
    // stage K tile [key][dh]
#pragma unroll
    for (int it = 0; it < 2; ++it) {
      int chunk = t + it * 256;
      int row = chunk >> 3, c8 = (chunk & 7) * 8;
      *reinterpret_cast<s16x8*>(&Ks[row][c8]) =
          *reinterpret_cast<const s16x8*>(Kp + (size_t)(kt + row) * 64 + c8);
    }
    // stage V transposed [dh][key]
    {
      int vkey = t & 63, vdb = (t >> 6) * 16;
      const unsigned short* vsrc = Vp + (size_t)(kt + vkey) * 64 + vdb;
      s16x8 v0 = *reinterpret_cast<const s16x8*>(vsrc);
      s16x8 v1 = *reinterpret_cast<const s16x8*>(vsrc + 8);
#pragma unroll
      for (int j = 0; j < 8; ++j) Vt[vdb + j][vkey] = (unsigned short)v0[j];
#pragma unroll
      for (int j = 0; j < 8; ++j) Vt[vdb + 8 + j][vkey] = (unsigned short)v1[j];
    }
    __syncthreads();
    // S = Q K^T (16 queries x 64 keys per wave)
    f32x4 sacc[4];
#pragma unroll
    for (int n = 0; n < 4; ++n) {
      f32x4 zz = {0.f,0.f,0.f,0.f};
      sacc[n] = zz;
      s16x8 kf0 = *reinterpret_cast<const s16x8*>(&Ks[n * 16 + mr][g * 8]);
      s16x8 kf1 = *reinterpret_cast<const s16x8*>(&Ks[n * 16 + mr][32 + g * 8]);
      sacc[n] = __builtin_amdgcn_mfma_f32_16x16x32_bf16(qf0, kf0, sacc[n], 0, 0, 0);
      sacc[n] = __builtin_amdgcn_mfma_f32_16x16x32_bf16(qf1, kf1, sacc[n], 0, 0, 0);
    }
    // mask + online softmax per query row (row = g*4+reg, lane-local stats)
#pragma unroll
    for (int reg = 0; reg < 4; ++reg) {
      int q_abs = qbase + g * 4 + reg;
      float vmax = -1e30f;
#pragma unroll
      for (int n = 0; n < 4; ++n) {
        int key = kt + n * 16 + mr;
        int dd = key - q_abs; dd = dd < 0 ? -dd : dd;
        float sv = (dd <= WIN_) ? sacc[n][reg] : -1e30f;
        sacc[n][reg] = sv;
        vmax = fmaxf(vmax, sv);
      }
#pragma unroll
      for (int off = 1; off < 16; off <<= 1) vmax = fmaxf(vmax, __shfl_xor(vmax, off));
      float nm = fmaxf(m_[reg], vmax);
      float sc = exp2f((m_[reg] - nm) * LOG2E_);
      float rsum = 0.f;
#pragma unroll
      for (int n = 0; n < 4; ++n) {
        float p = exp2f((sacc[n][reg] - nm) * LOG2E_);
        sacc[n][reg] = p;
        rsum += p;
      }
#pragma unroll
      for (int off = 1; off < 16; off <<= 1) rsum += __shfl_xor(rsum, off);
      l_[reg] = l_[reg] * sc + rsum;
      m_[reg] = nm;
#pragma unroll
      for (int fn = 0; fn < 4; ++fn) oacc[fn][reg] *= sc;
      // P -> bf16 into per-wave LDS (S-layout rows)
#pragma unroll
      for (int n = 0; n < 4; ++n)
        Ps[wid][g * 4 + reg][n * 16 + mr] = f2b(sacc[n][reg]);
    }
    // PV: A = P (row=mr query, k=key), B = Vt (row=dh, k=key)
    s16x8 pa0 = *reinterpret_cast<const s16x8*>(&Ps[wid][mr][g * 8]);
    s16x8 pa1 = *reinterpret_cast<const s16x8*>(&Ps[wid][mr][32 + g * 8]);
#pragma unroll
    for (int fn = 0; fn < 4; ++fn) {
      s16x8 vf0 = *reinterpret_cast<const s16x8*>(&Vt[fn * 16 + mr][g * 8]);
      s16x8 vf1 = *reinterpret_cast<const s16x8*>(&Vt[fn * 16 + mr][32 + g * 8]);
      oacc[fn] = __builtin_amdgcn_mfma_f32_16x16x32_bf16(pa0, vf0, oacc[fn], 0, 0, 0);
      oacc[fn] = __builtin_amdgcn_mfma_f32_16x16x32_bf16(pa1, vf1, oacc[fn], 0, 0, 0);
    }
  }
  // epilogue: normalize and store
#pragma unroll
  for (int reg = 0; reg < 4; ++reg) {
    float inv = 1.f / l_[reg];
    int q_abs = qbase + g * 4 + reg;
    unsigned short* dst = attnbf + ((size_t)(b * L_ + q_abs)) * 512 + h * 64;
#pragma unroll
    for (int fn = 0; fn < 4; ++fn)
      dst[fn * 16 + mr] = f2b(oacc[fn][reg] * inv);
  }
}

// ---------- weighted reduce of u over l-chunks: part[b][c][s] ----------
__global__ __launch_bounds__(256) void k_ured(const float* __restrict__ u,
                                              const float* __restrict__ Ap,
                                              float* __restrict__ part) {
  int c = blockIdx.x, b = blockIdx.y, s = threadIdx.x;
  float a = 1.f / (1.f + expf(-Ap[s]));
  float la = logf(a);
  float acc = 0.f;
  const float* up = u + (size_t)(b * L_ + c * 128) * S_ + s;
  int base = c * 128;
  for (int j = 0; j < 128; ++j) {
    float p = (float)(L_ - 1 - (base + j));
    acc += up[(size_t)j * S_] * expf(p * la);
  }
  part[(size_t)(b * 16 + c) * S_ + s] = acc;
}

// ---------- hT = a^L * h0 + sum_c part ----------
__global__ __launch_bounds__(256) void k_hT(const float* __restrict__ part,
                                            const float* __restrict__ h0,
                                            const float* __restrict__ Ap,
                                            float* __restrict__ hT, int hash0) {
  int b = blockIdx.x, s = threadIdx.x;
  float acc = 0.f;
  for (int c = 0; c < 16; ++c) acc += part[(size_t)(b * 16 + c) * S_ + s];
  if (hash0) {
    float a = 1.f / (1.f + expf(-Ap[s]));
    acc += expf(2048.f * logf(a)) * h0[b * S_ + s];
  }
  hT[b * S_ + s] = acc;
}

// ---------- state = hT @ Wout ----------
__global__ __launch_bounds__(256) void k_state(const float* __restrict__ hT,
                                               const float* __restrict__ Wout,
                                               float* __restrict__ state) {
  int b = blockIdx.x, t = threadIdx.x;
#pragma unroll
  for (int r = 0; r < 2; ++r) {
    int d = r * 256 + t;
    float acc = 0.f;
    for (int s = 0; s < S_; ++s) acc += hT[b * S_ + s] * Wout[(size_t)s * D_ + d];
    state[b * D_ + d] = acc;
  }
}

// ---------- LayerNorm(seq + add), in place; add is (B,D) or (B,L,D) ----------
__global__ __launch_bounds__(128) void k_ln(float* __restrict__ seq,
                                            const float* __restrict__ add, int addfull,
                                            const float* __restrict__ gamma,
                                            const float* __restrict__ beta) {
  int bl = blockIdx.x;
  int b = bl >> 11;
  int t = threadIdx.x;
  float4 v = reinterpret_cast<float4*>(seq)[(size_t)bl * 128 + t];
  const float4* a4 = reinterpret_cast<const float4*>(add);
  float4 a = addfull ? a4[(size_t)bl * 128 + t] : a4[b * 128 + t];
  v.x += a.x; v.y += a.y; v.z += a.z; v.w += a.w;
  float s = v.x + v.y + v.z + v.w;
  float s2 = v.x * v.x + v.y * v.y + v.z * v.z + v.w * v.w;
#pragma unroll
  for (int off = 32; off >= 1; off >>= 1) {
    s += __shfl_down(s, off);
    s2 += __shfl_down(s2, off);
  }
  __shared__ float r1[2], r2[2];
  if ((t & 63) == 0) { r1[t >> 6] = s; r2[t >> 6] = s2; }
  __syncthreads();
  float fs = r1[0] + r1[1], fq = r2[0] + r2[1];
  float mu = fs * (1.f / D_);
  float var = fq * (1.f / D_) - mu * mu;
  float rstd = rsqrtf(var + EPS_);
  float4 g = reinterpret_cast<const float4*>(gamma)[t];
  float4 be = reinterpret_cast<const float4*>(beta)[t];
  float4 o;
  o.x = (v.x - mu) * rstd * g.x + be.x;
  o.y = (v.y - mu) * rstd * g.y + be.y;
  o.z = (v.z - mu) * rstd * g.z + be.z;
  o.w = (v.w - mu) * rstd * g.w + be.w;
  reinterpret_cast<float4*>(seq)[(size_t)bl * 128 + t] = o;
}

extern "C" void kernel_launch(void* const* d_in, const int* in_sizes, int n_in,
                              void* d_out, int out_size, void* d_ws, size_t ws_size,
                              hipStream_t stream) {
  const float* context = (const float*)d_in[0];
  const float* conv_w  = (const float*)d_in[1];
  const float* Wx      = (const float*)d_in[2];
  const float* Wh      = (const float*)d_in[3];
  const float* Wout    = (const float*)d_in[4];
  const float* Aparm   = (const float*)d_in[5];
  const float* gamma_m = (const float*)d_in[6];
  const float* beta_m  = (const float*)d_in[7];
  const float* gamma_a = (const float*)d_in[8];
  const float* beta_a  = (const float*)d_in[9];
  const float* Wqkv    = (const float*)d_in[10];
  const float* bqkv    = (const float*)d_in[11];
  const float* Wo      = (const float*)d_in[12];
  const float* bo      = (const float*)d_in[13];
  float* seq = (float*)d_out;
  float* ws = (float*)d_ws;

  // ws layout (floats). Aliased regions are temporally disjoint, stream-ordered:
  //   u (mamba, consumed by k_ured) aliases proj (attn out-proj f32, layer 3 only)
  //   sbf: seqbf (A of QKV GEMM) aliases attnbf (written after QKV GEMM completes)
  float* u    = ws;                                   // 2,097,152 floats
  float* proj = ws;                                   // 4,194,304 floats (alias)
  unsigned short* Qbf    = (unsigned short*)(ws + 4194304);   // 4,194,304 bf16
  unsigned short* Kbf    = (unsigned short*)(ws + 6291456);
  unsigned short* Vbf    = (unsigned short*)(ws + 8388608);
  unsigned short* xbf    = (unsigned short*)(ws + 10485760);
  unsigned short* sbf    = (unsigned short*)(ws + 12582912);  // seqbf / attnbf
  unsigned short* wqkvbf = (unsigned short*)(ws + 14680064);
  unsigned short* wobf   = (unsigned short*)(ws + 15073280);
  unsigned short* wxtbf  = (unsigned short*)(ws + 15204352);
  float* state = ws + 15597568;
  float* h0    = state + 2048;
  float* hT    = h0 + 1024;
  float* part  = hT + 1024;

  hipMemcpyAsync(seq, context, (size_t)B_ * L_ * D_ * 4, hipMemcpyDeviceToDevice, stream);
  k_f2b<<<768, 256, 0, stream>>>(Wqkv, wqkvbf, 196608);
  k_f2b<<<256, 256, 0, stream>>>(Wo, wobf, 65536);
  k_twx<<<dim3(16, 8, 6), dim3(32, 8), 0, stream>>>(Wx, wxtbf);

  for (int i = 0; i < 6; ++i) {
    k_conv_silu<<<B_ * L_, 128, 0, stream>>>(seq, conv_w + (size_t)i * 3 * D_, xbf);
    if (i > 0) k_h0<<<B_, 256, 0, stream>>>(state, Wh + (size_t)i * D_ * S_, h0);
    k_gemm<<<dim3(128, 4), 256, 0, stream>>>(xbf, wxtbf + (size_t)i * S_ * D_, u, nullptr, 8192, 256, 512);
    k_ured<<<dim3(16, 4), 256, 0, stream>>>(u, Aparm + (size_t)i * S_, part);
    k_hT<<<B_, 256, 0, stream>>>(part, h0, Aparm + (size_t)i * S_, hT, i > 0 ? 1 : 0);
    k_state<<<B_, 256, 0, stream>>>(hT, Wout + (size_t)i * S_ * D_, state);
    k_ln<<<B_ * L_, 128, 0, stream>>>(seq, state, 0, gamma_m, beta_m);
    if (i == 3) {
      k_f2b<<<4096, 256, 0, stream>>>(seq, sbf, 1048576);
      k_gemm_qkv<<<dim3(128, 24), 256, 0, stream>>>(sbf, wqkvbf, bqkv, Qbf, Kbf, Vbf);
      k_fattn<<<dim3(32, 8, 4), 256, 0, stream>>>(Qbf, Kbf, Vbf, sbf);
      k_gemm<<<dim3(128, 8), 256, 0, stream>>>(sbf, wobf, proj, bo, 8192, 512, 512);
      k_ln<<<B_ * L_, 128, 0, stream>>>(seq, proj, 1, gamma_a, beta_a);
    }
  }
}

// Round 3
// 470.199 us; speedup vs baseline: 8.5383x; 1.2952x over previous
//
#include <hip/hip_runtime.h>

#define B_ 4
#define L_ 2048
#define D_ 512
#define S_ 256
#define H_ 8
#define DH_ 64
#define WIN_ 256
#define EPS_ 1e-5f
#define LOG2E_ 1.4426950408889634f

using f32x4 = __attribute__((ext_vector_type(4))) float;
using s16x8 = __attribute__((ext_vector_type(8))) short;

__device__ __forceinline__ unsigned short f2b(float f) {
  unsigned int u = __builtin_bit_cast(unsigned int, f);
  u += 0x7FFFu + ((u >> 16) & 1u);   // RNE to bf16 (inputs finite)
  return (unsigned short)(u >> 16);
}

// ---------- f32 -> bf16 convert (n4 = n/4) ----------
__global__ __launch_bounds__(256) void k_f2b(const float* __restrict__ in,
                                             unsigned short* __restrict__ out, int n4) {
  int i = blockIdx.x * 256 + threadIdx.x;
  if (i >= n4) return;
  float4 v = reinterpret_cast<const float4*>(in)[i];
  ushort4 o;
  o.x = f2b(v.x); o.y = f2b(v.y); o.z = f2b(v.z); o.w = f2b(v.w);
  reinterpret_cast<ushort4*>(out)[i] = o;
}

// ---------- transpose+convert Wx (NL,D,S) -> (NL,S,D) bf16 ----------
__global__ void k_twx(const float* __restrict__ wx, unsigned short* __restrict__ wxt) {
  __shared__ float tile[32][33];
  int lyr = blockIdx.z;
  int d0 = blockIdx.x * 32, s0 = blockIdx.y * 32;
  const float* src = wx + (size_t)lyr * D_ * S_;
  unsigned short* dst = wxt + (size_t)lyr * S_ * D_;
  for (int r = threadIdx.y; r < 32; r += 8)
    tile[r][threadIdx.x] = src[(size_t)(d0 + r) * S_ + s0 + threadIdx.x];
  __syncthreads();
  for (int r = threadIdx.y; r < 32; r += 8)
    dst[(size_t)(s0 + r) * D_ + d0 + threadIdx.x] = f2b(tile[threadIdx.x][r]);
}

// ---------- causal depthwise conv (k=3) + SiLU, write bf16 ----------
__global__ __launch_bounds__(128) void k_conv_silu(const float* __restrict__ seq,
                                                   const float* __restrict__ cw,
                                                   unsigned short* __restrict__ x) {
  int bl = blockIdx.x;
  int l = bl & (L_ - 1);
  int t = threadIdx.x;
  const float4* s4 = reinterpret_cast<const float4*>(seq);
  const float4* c4 = reinterpret_cast<const float4*>(cw);
  size_t row = (size_t)bl * 128;
  float4 c0 = c4[t], c1 = c4[128 + t], c2 = c4[256 + t];
  float4 z = make_float4(0.f, 0.f, 0.f, 0.f);
  float4 s0 = (l >= 2) ? s4[row - 256 + t] : z;
  float4 s1 = (l >= 1) ? s4[row - 128 + t] : z;
  float4 s2 = s4[row + t];
  float y0 = c0.x * s0.x + c1.x * s1.x + c2.x * s2.x;
  float y1 = c0.y * s0.y + c1.y * s1.y + c2.y * s2.y;
  float y2 = c0.z * s0.z + c1.z * s1.z + c2.z * s2.z;
  float y3 = c0.w * s0.w + c1.w * s1.w + c2.w * s2.w;
  float v0 = y0 / (1.f + expf(-y0));
  float v1 = y1 / (1.f + expf(-y1));
  float v2 = y2 / (1.f + expf(-y2));
  float v3 = y3 / (1.f + expf(-y3));
  ushort4 o;
  o.x = f2b(v0); o.y = f2b(v1); o.z = f2b(v2); o.w = f2b(v3);
  reinterpret_cast<ushort4*>(x)[row + t] = o;
}

// ---------- 128x128 bf16 MFMA GEMM core (reg-staged, single-buffered) ----------
// 256 threads = 4 waves (2x2); each wave owns a 64x64 quadrant = 4x4 fragments.
__device__ __forceinline__ void g128_core(const unsigned short* __restrict__ A,
                                          const unsigned short* __restrict__ Bt,
                                          int K, int m0, int n0,
                                          unsigned short* As, unsigned short* Bs,
                                          f32x4 (&acc)[4][4]) {
  int t = threadIdx.x;
  int lane = t & 63;
  int g = lane >> 4, mr = lane & 15;
  int wid = t >> 6, wr = wid >> 1, wc = wid & 1;
#pragma unroll
  for (int i = 0; i < 4; ++i)
#pragma unroll
    for (int j = 0; j < 4; ++j) { f32x4 z = {0.f, 0.f, 0.f, 0.f}; acc[i][j] = z; }
  // staging: chunk c (16B) -> row c>>2, colpart c&3; thread t stages chunks t, t+256
  int r0 = t >> 2, p = (t & 3) * 8;
  const unsigned short* ag0 = A + (size_t)(m0 + r0) * K + p;
  const unsigned short* ag1 = A + (size_t)(m0 + r0 + 64) * K + p;
  const unsigned short* bg0 = Bt + (size_t)(n0 + r0) * K + p;
  const unsigned short* bg1 = Bt + (size_t)(n0 + r0 + 64) * K + p;
  for (int k0 = 0; k0 < K; k0 += 32) {
    s16x8 a0 = *reinterpret_cast<const s16x8*>(ag0 + k0);
    s16x8 a1 = *reinterpret_cast<const s16x8*>(ag1 + k0);
    s16x8 b0 = *reinterpret_cast<const s16x8*>(bg0 + k0);
    s16x8 b1 = *reinterpret_cast<const s16x8*>(bg1 + k0);
    __syncthreads();
    *reinterpret_cast<s16x8*>(As + (size_t)t * 8) = a0;
    *reinterpret_cast<s16x8*>(As + (size_t)(t + 256) * 8) = a1;
    *reinterpret_cast<s16x8*>(Bs + (size_t)t * 8) = b0;
    *reinterpret_cast<s16x8*>(Bs + (size_t)(t + 256) * 8) = b1;
    __syncthreads();
    s16x8 af[4], bf[4];
#pragma unroll
    for (int fm = 0; fm < 4; ++fm)
      af[fm] = *reinterpret_cast<const s16x8*>(As + (size_t)(wr * 64 + fm * 16 + mr) * 32 + g * 8);
#pragma unroll
    for (int fn = 0; fn < 4; ++fn)
      bf[fn] = *reinterpret_cast<const s16x8*>(Bs + (size_t)(wc * 64 + fn * 16 + mr) * 32 + g * 8);
#pragma unroll
    for (int fm = 0; fm < 4; ++fm)
#pragma unroll
      for (int fn = 0; fn < 4; ++fn)
        acc[fm][fn] = __builtin_amdgcn_mfma_f32_16x16x32_bf16(af[fm], bf[fn], acc[fm][fn], 0, 0, 0);
  }
}

// ---------- plain C = A*Bt^T (+bias), f32 out ----------
__global__ __launch_bounds__(256) void k_g128(const unsigned short* __restrict__ A,
                                              const unsigned short* __restrict__ Bt,
                                              float* __restrict__ C,
                                              const float* __restrict__ bias,
                                              int N, int K) {
  __shared__ __align__(16) unsigned short As[4096], Bs[4096];
  int m0 = blockIdx.x * 128, n0 = blockIdx.y * 128;
  f32x4 acc[4][4];
  g128_core(A, Bt, K, m0, n0, As, Bs, acc);
  int t = threadIdx.x, lane = t & 63, g = lane >> 4, mr = lane & 15;
  int wid = t >> 6, wr = wid >> 1, wc = wid & 1;
#pragma unroll
  for (int fm = 0; fm < 4; ++fm)
#pragma unroll
    for (int fn = 0; fn < 4; ++fn) {
      int row = m0 + wr * 64 + fm * 16 + g * 4;
      int col = n0 + wc * 64 + fn * 16 + mr;
      float badd = bias ? bias[col] : 0.f;
#pragma unroll
      for (int q = 0; q < 4; ++q)
        C[(size_t)(row + q) * N + col] = acc[fm][fn][q] + badd;
    }
}

// ---------- QKV GEMM, epilogue splits into Q(scaled)/K/V bf16 [B,H,L,64] ----------
__global__ __launch_bounds__(256) void k_g128_qkv(const unsigned short* __restrict__ A,
                                                  const unsigned short* __restrict__ Bt,
                                                  const float* __restrict__ bias,
                                                  unsigned short* __restrict__ Qbf,
                                                  unsigned short* __restrict__ Kbf,
                                                  unsigned short* __restrict__ Vbf) {
  __shared__ __align__(16) unsigned short As[4096], Bs[4096];
  int m0 = blockIdx.x * 128, n0 = blockIdx.y * 128;
  f32x4 acc[4][4];
  g128_core(A, Bt, 512, m0, n0, As, Bs, acc);
  int t = threadIdx.x, lane = t & 63, g = lane >> 4, mr = lane & 15;
  int wid = t >> 6, wr = wid >> 1, wc = wid & 1;
#pragma unroll
  for (int fm = 0; fm < 4; ++fm)
#pragma unroll
    for (int fn = 0; fn < 4; ++fn) {
      int row0 = m0 + wr * 64 + fm * 16 + g * 4;
      int col = n0 + wc * 64 + fn * 16 + mr;
      int sec = col >> 9;           // 0=Q 1=K 2=V
      int hh = (col >> 6) & 7;
      int dh = col & 63;
      float badd = bias[col];
      float scale = (sec == 0) ? 0.125f : 1.f;
      unsigned short* dstbase = (sec == 0) ? Qbf : (sec == 1 ? Kbf : Vbf);
#pragma unroll
      for (int q = 0; q < 4; ++q) {
        int row = row0 + q;
        int b = row >> 11, l = row & 2047;
        dstbase[(((size_t)(b * H_ + hh)) * L_ + l) * 64 + dh] =
            f2b((acc[fm][fn][q] + badd) * scale);
      }
    }
}

// ---------- u GEMM with fused decay-weighted row reduction ----------
// part2[b][mchunk][s] = sum over this block's 128 rows of u[row][s] * a(s)^(2047-l)
__global__ __launch_bounds__(256) void k_g128_u(const unsigned short* __restrict__ A,
                                                const unsigned short* __restrict__ Bt,
                                                const float* __restrict__ Ap,
                                                float* __restrict__ part2) {
  __shared__ __align__(16) unsigned short As[4096], Bs[4096];
  int m0 = blockIdx.x * 128, n0 = blockIdx.y * 128;
  f32x4 acc[4][4];
  g128_core(A, Bt, 512, m0, n0, As, Bs, acc);
  int t = threadIdx.x, lane = t & 63, g = lane >> 4, mr = lane & 15;
  int wid = t >> 6, wr = wid >> 1, wc = wid & 1;
  int b = m0 >> 11, mchunk = (m0 >> 7) & 15;
  float wsum[4];
#pragma unroll
  for (int fn = 0; fn < 4; ++fn) {
    int col = n0 + wc * 64 + fn * 16 + mr;
    float a = 1.f / (1.f + expf(-Ap[col]));
    float la2 = log2f(a);
    float s = 0.f;
#pragma unroll
    for (int fm = 0; fm < 4; ++fm) {
      int rbase = (m0 + wr * 64 + fm * 16 + g * 4) & 2047;
#pragma unroll
      for (int q = 0; q < 4; ++q) {
        float e = (float)(2047 - (rbase + q));
        s += acc[fm][fn][q] * exp2f(e * la2);
      }
    }
    // reduce over g (lane bits 4,5): 4 lanes hold the wave's 64 rows
    s += __shfl_xor(s, 16);
    s += __shfl_xor(s, 32);
    wsum[fn] = s;
  }
  // cross-wave (wr 0/1) combine in fixed order -> deterministic
  float* red = (float*)As;
  __syncthreads();
  if (wr == 0 && g == 0) {
#pragma unroll
    for (int fn = 0; fn < 4; ++fn) red[(wc * 4 + fn) * 16 + mr] = wsum[fn];
  }
  __syncthreads();
  if (wr == 1 && g == 0) {
#pragma unroll
    for (int fn = 0; fn < 4; ++fn) {
      int col = n0 + wc * 64 + fn * 16 + mr;
      part2[(size_t)(b * 16 + mchunk) * 256 + col] =
          wsum[fn] + red[(wc * 4 + fn) * 16 + mr];
    }
  }
}

// ---------- fused mamba tail: h0 = state@Wh; hT = a^L h0 + sum part2; state = hT@Wout ----------
__global__ __launch_bounds__(256) void k_tail(float* __restrict__ state,
                                              const float* __restrict__ Wh,
                                              const float* __restrict__ Wout,
                                              const float* __restrict__ Ap,
                                              const float* __restrict__ part2,
                                              int use_h0) {
  int b = blockIdx.x, t = threadIdx.x;
  __shared__ float sst[512];
  __shared__ float hTs[256];
  float h0v = 0.f;
  if (use_h0) {
    sst[t] = state[b * 512 + t];
    sst[t + 256] = state[b * 512 + t + 256];
    __syncthreads();
    for (int d = 0; d < 512; ++d) h0v += sst[d] * Wh[(size_t)d * 256 + t];
  }
  float acc = 0.f;
  for (int c = 0; c < 16; ++c) acc += part2[(size_t)(b * 16 + c) * 256 + t];
  if (use_h0) {
    float a = 1.f / (1.f + expf(-Ap[t]));
    acc += exp2f(2048.f * log2f(a)) * h0v;
  }
  hTs[t] = acc;
  __syncthreads();
#pragma unroll
  for (int r = 0; r < 2; ++r) {
    int d = r * 256 + t;
    float s = 0.f;
    for (int ss = 0; ss < 256; ++ss) s += hTs[ss] * Wout[(size_t)ss * 512 + d];
    state[b * 512 + d] = s;
  }
}

// ---------- LayerNorm(seq + add), in place; optional bf16 copy-out ----------
__global__ __launch_bounds__(128) void k_ln(float* __restrict__ seq,
                                            const float* __restrict__ add, int addfull,
                                            const float* __restrict__ gamma,
                                            const float* __restrict__ beta,
                                            unsigned short* __restrict__ outbf) {
  int bl = blockIdx.x;
  int b = bl >> 11;
  int t = threadIdx.x;
  float4 v = reinterpret_cast<float4*>(seq)[(size_t)bl * 128 + t];
  const float4* a4 = reinterpret_cast<const float4*>(add);
  float4 a = addfull ? a4[(size_t)bl * 128 + t] : a4[b * 128 + t];
  v.x += a.x; v.y += a.y; v.z += a.z; v.w += a.w;
  float s = v.x + v.y + v.z + v.w;
  float s2 = v.x * v.x + v.y * v.y + v.z * v.z + v.w * v.w;
#pragma unroll
  for (int off = 32; off >= 1; off >>= 1) {
    s += __shfl_down(s, off);
    s2 += __shfl_down(s2, off);
  }
  __shared__ float r1[2], r2[2];
  if ((t & 63) == 0) { r1[t >> 6] = s; r2[t >> 6] = s2; }
  __syncthreads();
  float fs = r1[0] + r1[1], fq = r2[0] + r2[1];
  float mu = fs * (1.f / D_);
  float var = fq * (1.f / D_) - mu * mu;
  float rstd = rsqrtf(var + EPS_);
  float4 g = reinterpret_cast<const float4*>(gamma)[t];
  float4 be = reinterpret_cast<const float4*>(beta)[t];
  float4 o;
  o.x = (v.x - mu) * rstd * g.x + be.x;
  o.y = (v.y - mu) * rstd * g.y + be.y;
  o.z = (v.z - mu) * rstd * g.z + be.z;
  o.w = (v.w - mu) * rstd * g.w + be.w;
  reinterpret_cast<float4*>(seq)[(size_t)bl * 128 + t] = o;
  if (outbf) {
    ushort4 ob;
    ob.x = f2b(o.x); ob.y = f2b(o.y); ob.z = f2b(o.z); ob.w = f2b(o.w);
    reinterpret_cast<ushort4*>(outbf)[(size_t)bl * 128 + t] = ob;
  }
}

// ---------- flash banded attention: Q/K/V bf16 [B,H,L,64] -> attnbf [B,L,512] ----------
__global__ __launch_bounds__(256) void k_fattn(const unsigned short* __restrict__ Qbf,
                                               const unsigned short* __restrict__ Kbf,
                                               const unsigned short* __restrict__ Vbf,
                                               unsigned short* __restrict__ attnbf) {
  __shared__ __align__(16) unsigned short Ks[64][72];
  __shared__ __align__(16) unsigned short Vt[64][72];
  __shared__ __align__(16) unsigned short Ps[4][16][72];
  int b = blockIdx.z, h = blockIdx.y, q0 = blockIdx.x * 64;
  int t = threadIdx.x;
  int lane = t & 63, wid = t >> 6;
  int g = lane >> 4, mr = lane & 15;
  const unsigned short* Qp = Qbf + ((size_t)(b * H_ + h)) * L_ * 64;
  const unsigned short* Kp = Kbf + ((size_t)(b * H_ + h)) * L_ * 64;
  const unsigned short* Vp = Vbf + ((size_t)(b * H_ + h)) * L_ * 64;
  int qbase = q0 + wid * 16;
  s16x8 qf0 = *reinterpret_cast<const s16x8*>(Qp + (size_t)(qbase + mr) * 64 + g * 8);
  s16x8 qf1 = *reinterpret_cast<const s16x8*>(Qp + (size_t)(qbase + mr) * 64 + 32 + g * 8);
  f32x4 oacc[4];
#pragma unroll
  for (int fn = 0; fn < 4; ++fn) { f32x4 zz = {0.f,0.f,0.f,0.f}; oacc[fn] = zz; }
  float m_[4] = {-1e30f, -1e30f, -1e30f, -1e30f};
  float l_[4] = {0.f, 0.f, 0.f, 0.f};
  int kstart = q0 - WIN_; if (kstart < 0) kstart = 0;
  int kend = q0 + 64 + WIN_; if (kend > L_) kend = L_;

  for (int kt = kstart; kt < kend; kt += 64) {
    __syncthreads();
#pragma unroll
    for (int it = 0; it < 2; ++it) {
      int chunk = t + it * 256;
      int row = chunk >> 3, c8 = (chunk & 7) * 8;
      *reinterpret_cast<s16x8*>(&Ks[row][c8]) =
          *reinterpret_cast<const s16x8*>(Kp + (size_t)(kt + row) * 64 + c8);
    }
    {
      int vkey = t & 63, vdb = (t >> 6) * 16;
      const unsigned short* vsrc = Vp + (size_t)(kt + vkey) * 64 + vdb;
      s16x8 v0 = *reinterpret_cast<const s16x8*>(vsrc);
      s16x8 v1 = *reinterpret_cast<const s16x8*>(vsrc + 8);
#pragma unroll
      for (int j = 0; j < 8; ++j) Vt[vdb + j][vkey] = (unsigned short)v0[j];
#pragma unroll
      for (int j = 0; j < 8; ++j) Vt[vdb + 8 + j][vkey] = (unsigned short)v1[j];
    }
    __syncthreads();
    f32x4 sacc[4];
#pragma unroll
    for (int n = 0; n < 4; ++n) {
      f32x4 zz = {0.f,0.f,0.f,0.f};
      sacc[n] = zz;
      s16x8 kf0 = *reinterpret_cast<const s16x8*>(&Ks[n * 16 + mr][g * 8]);
      s16x8 kf1 = *reinterpret_cast<const s16x8*>(&Ks[n * 16 + mr][32 + g * 8]);
      sacc[n] = __builtin_amdgcn_mfma_f32_16x16x32_bf16(qf0, kf0, sacc[n], 0, 0, 0);
      sacc[n] = __builtin_amdgcn_mfma_f32_16x16x32_bf16(qf1, kf1, sacc[n], 0, 0, 0);
    }
#pragma unroll
    for (int reg = 0; reg < 4; ++reg) {
      int q_abs = qbase + g * 4 + reg;
      float vmax = -1e30f;
#pragma unroll
      for (int n = 0; n < 4; ++n) {
        int key = kt + n * 16 + mr;
        int dd = key - q_abs; dd = dd < 0 ? -dd : dd;
        float sv = (dd <= WIN_) ? sacc[n][reg] : -1e30f;
        sacc[n][reg] = sv;
        vmax = fmaxf(vmax, sv);
      }
#pragma unroll
      for (int off = 1; off < 16; off <<= 1) vmax = fmaxf(vmax, __shfl_xor(vmax, off));
      float nm = fmaxf(m_[reg], vmax);
      float sc = exp2f((m_[reg] - nm) * LOG2E_);
      float rsum = 0.f;
#pragma unroll
      for (int n = 0; n < 4; ++n) {
        float p = exp2f((sacc[n][reg] - nm) * LOG2E_);
        sacc[n][reg] = p;
        rsum += p;
      }
#pragma unroll
      for (int off = 1; off < 16; off <<= 1) rsum += __shfl_xor(rsum, off);
      l_[reg] = l_[reg] * sc + rsum;
      m_[reg] = nm;
#pragma unroll
      for (int fn = 0; fn < 4; ++fn) oacc[fn][reg] *= sc;
#pragma unroll
      for (int n = 0; n < 4; ++n)
        Ps[wid][g * 4 + reg][n * 16 + mr] = f2b(sacc[n][reg]);
    }
    s16x8 pa0 = *reinterpret_cast<const s16x8*>(&Ps[wid][mr][g * 8]);
    s16x8 pa1 = *reinterpret_cast<const s16x8*>(&Ps[wid][mr][32 + g * 8]);
#pragma unroll
    for (int fn = 0; fn < 4; ++fn) {
      s16x8 vf0 = *reinterpret_cast<const s16x8*>(&Vt[fn * 16 + mr][g * 8]);
      s16x8 vf1 = *reinterpret_cast<const s16x8*>(&Vt[fn * 16 + mr][32 + g * 8]);
      oacc[fn] = __builtin_amdgcn_mfma_f32_16x16x32_bf16(pa0, vf0, oacc[fn], 0, 0, 0);
      oacc[fn] = __builtin_amdgcn_mfma_f32_16x16x32_bf16(pa1, vf1, oacc[fn], 0, 0, 0);
    }
  }
#pragma unroll
  for (int reg = 0; reg < 4; ++reg) {
    float inv = 1.f / l_[reg];
    int q_abs = qbase + g * 4 + reg;
    unsigned short* dst = attnbf + ((size_t)(b * L_ + q_abs)) * 512 + h * 64;
#pragma unroll
    for (int fn = 0; fn < 4; ++fn)
      dst[fn * 16 + mr] = f2b(oacc[fn][reg] * inv);
  }
}

extern "C" void kernel_launch(void* const* d_in, const int* in_sizes, int n_in,
                              void* d_out, int out_size, void* d_ws, size_t ws_size,
                              hipStream_t stream) {
  const float* context = (const float*)d_in[0];
  const float* conv_w  = (const float*)d_in[1];
  const float* Wx      = (const float*)d_in[2];
  const float* Wh      = (const float*)d_in[3];
  const float* Wout    = (const float*)d_in[4];
  const float* Aparm   = (const float*)d_in[5];
  const float* gamma_m = (const float*)d_in[6];
  const float* beta_m  = (const float*)d_in[7];
  const float* gamma_a = (const float*)d_in[8];
  const float* beta_a  = (const float*)d_in[9];
  const float* Wqkv    = (const float*)d_in[10];
  const float* bqkv    = (const float*)d_in[11];
  const float* Wo      = (const float*)d_in[12];
  const float* bo      = (const float*)d_in[13];
  float* seq = (float*)d_out;
  float* ws = (float*)d_ws;

  // ws layout (floats). proj (layer-3 f32 attn out-proj) is only live in the
  // attention phase; all other regions are disjoint.
  float* proj = ws;                                           // 4,194,304
  unsigned short* Qbf    = (unsigned short*)(ws + 4194304);   // 4,194,304 bf16
  unsigned short* Kbf    = (unsigned short*)(ws + 6291456);
  unsigned short* Vbf    = (unsigned short*)(ws + 8388608);
  unsigned short* xbf    = (unsigned short*)(ws + 10485760);
  unsigned short* sbf    = (unsigned short*)(ws + 12582912);  // seq bf16 / attn out bf16
  unsigned short* wqkvbf = (unsigned short*)(ws + 14680064);
  unsigned short* wobf   = (unsigned short*)(ws + 15073280);
  unsigned short* wxtbf  = (unsigned short*)(ws + 15204352);
  float* state = ws + 15597568;                               // 2048
  float* part2 = state + 2048;                                // 16384

  hipMemcpyAsync(seq, context, (size_t)B_ * L_ * D_ * 4, hipMemcpyDeviceToDevice, stream);
  k_f2b<<<768, 256, 0, stream>>>(Wqkv, wqkvbf, 196608);
  k_f2b<<<256, 256, 0, stream>>>(Wo, wobf, 65536);
  k_twx<<<dim3(16, 8, 6), dim3(32, 8), 0, stream>>>(Wx, wxtbf);

  for (int i = 0; i < 6; ++i) {
    k_conv_silu<<<B_ * L_, 128, 0, stream>>>(seq, conv_w + (size_t)i * 3 * D_, xbf);
    k_g128_u<<<dim3(64, 2), 256, 0, stream>>>(xbf, wxtbf + (size_t)i * S_ * D_,
                                              Aparm + (size_t)i * S_, part2);
    k_tail<<<B_, 256, 0, stream>>>(state, Wh + (size_t)i * D_ * S_,
                                   Wout + (size_t)i * S_ * D_,
                                   Aparm + (size_t)i * S_, part2, i > 0 ? 1 : 0);
    k_ln<<<B_ * L_, 128, 0, stream>>>(seq, state, 0, gamma_m, beta_m,
                                      (i == 3) ? sbf : nullptr);
    if (i == 3) {
      k_g128_qkv<<<dim3(64, 12), 256, 0, stream>>>(sbf, wqkvbf, bqkv, Qbf, Kbf, Vbf);
      k_fattn<<<dim3(32, 8, 4), 256, 0, stream>>>(Qbf, Kbf, Vbf, sbf);
      k_g128<<<dim3(64, 4), 256, 0, stream>>>(sbf, wobf, proj, bo, 512, 512);
      k_ln<<<B_ * L_, 128, 0, stream>>>(seq, proj, 1, gamma_a, beta_a, nullptr);
    }
  }
}

// Round 4
// 454.275 us; speedup vs baseline: 8.8376x; 1.0351x over previous
//
#include <hip/hip_runtime.h>

#define B_ 4
#define L_ 2048
#define D_ 512
#define S_ 256
#define H_ 8
#define DH_ 64
#define WIN_ 256
#define EPS_ 1e-5f
#define LOG2E_ 1.4426950408889634f

using f32x4 = __attribute__((ext_vector_type(4))) float;
using s16x8 = __attribute__((ext_vector_type(8))) short;

__device__ __forceinline__ unsigned short f2b(float f) {
  unsigned int u = __builtin_bit_cast(unsigned int, f);
  u += 0x7FFFu + ((u >> 16) & 1u);   // RNE to bf16 (inputs finite)
  return (unsigned short)(u >> 16);
}

__device__ __forceinline__ float silu(float y) { return y / (1.f + expf(-y)); }

// ---------- f32 -> bf16 convert (n4 = n/4) ----------
__global__ __launch_bounds__(256) void k_f2b(const float* __restrict__ in,
                                             unsigned short* __restrict__ out, int n4) {
  int i = blockIdx.x * 256 + threadIdx.x;
  if (i >= n4) return;
  float4 v = reinterpret_cast<const float4*>(in)[i];
  ushort4 o;
  o.x = f2b(v.x); o.y = f2b(v.y); o.z = f2b(v.z); o.w = f2b(v.w);
  reinterpret_cast<ushort4*>(out)[i] = o;
}

// ---------- transpose+convert Wx (NL,D,S) -> (NL,S,D) bf16 ----------
__global__ void k_twx(const float* __restrict__ wx, unsigned short* __restrict__ wxt) {
  __shared__ float tile[32][33];
  int lyr = blockIdx.z;
  int d0 = blockIdx.x * 32, s0 = blockIdx.y * 32;
  const float* src = wx + (size_t)lyr * D_ * S_;
  unsigned short* dst = wxt + (size_t)lyr * S_ * D_;
  for (int r = threadIdx.y; r < 32; r += 8)
    tile[r][threadIdx.x] = src[(size_t)(d0 + r) * S_ + s0 + threadIdx.x];
  __syncthreads();
  for (int r = threadIdx.y; r < 32; r += 8)
    dst[(size_t)(s0 + r) * D_ + d0 + threadIdx.x] = f2b(tile[threadIdx.x][r]);
}

// ---------- causal depthwise conv (k=3) + SiLU, layer-0 (reads context) ----------
__global__ __launch_bounds__(128) void k_conv_silu(const float* __restrict__ seq,
                                                   const float* __restrict__ cw,
                                                   unsigned short* __restrict__ x) {
  int bl = blockIdx.x;
  int l = bl & (L_ - 1);
  int t = threadIdx.x;
  const float4* s4 = reinterpret_cast<const float4*>(seq);
  const float4* c4 = reinterpret_cast<const float4*>(cw);
  size_t row = (size_t)bl * 128;
  float4 c0 = c4[t], c1 = c4[128 + t], c2 = c4[256 + t];
  float4 z = make_float4(0.f, 0.f, 0.f, 0.f);
  float4 s0 = (l >= 2) ? s4[row - 256 + t] : z;
  float4 s1 = (l >= 1) ? s4[row - 128 + t] : z;
  float4 s2 = s4[row + t];
  float y0 = c0.x * s0.x + c1.x * s1.x + c2.x * s2.x;
  float y1 = c0.y * s0.y + c1.y * s1.y + c2.y * s2.y;
  float y2 = c0.z * s0.z + c1.z * s1.z + c2.z * s2.z;
  float y3 = c0.w * s0.w + c1.w * s1.w + c2.w * s2.w;
  ushort4 o;
  o.x = f2b(silu(y0)); o.y = f2b(silu(y1)); o.z = f2b(silu(y2)); o.w = f2b(silu(y3));
  reinterpret_cast<ushort4*>(x)[row + t] = o;
}

// ---------- fused LayerNorm(seqIn + add) -> seqOut [+bf16 mirror] [+conv(k=3)+SiLU -> xbf] ----------
// 1 wave per block; each wave owns an 8-row strip (plus 2 halo rows when conv on).
// All blocks read seqIn, write seqOut (ping-pong) -> no halo race. In-place only legal w/o conv.
__global__ __launch_bounds__(64) void k_lnconv(const float* __restrict__ seqIn,
                                               const float* __restrict__ add, int addfull,
                                               const float* __restrict__ gamma,
                                               const float* __restrict__ beta,
                                               float* __restrict__ seqOut,
                                               unsigned short* __restrict__ xbf,
                                               const float* __restrict__ cw,
                                               unsigned short* __restrict__ sbf) {
  int t = threadIdx.x;
  int r0 = blockIdx.x * 8;
  int b = r0 >> 11, l0 = r0 & (L_ - 1);
  bool hasconv = (cw != nullptr);
  const float4* in4 = reinterpret_cast<const float4*>(seqIn);
  const float4* ad4 = reinterpret_cast<const float4*>(add);
  float4* out4 = reinterpret_cast<float4*>(seqOut);
  float4 g0 = reinterpret_cast<const float4*>(gamma)[2 * t];
  float4 g1 = reinterpret_cast<const float4*>(gamma)[2 * t + 1];
  float4 be0 = reinterpret_cast<const float4*>(beta)[2 * t];
  float4 be1 = reinterpret_cast<const float4*>(beta)[2 * t + 1];
  float4 av0, av1;
  if (!addfull) { av0 = ad4[b * 128 + 2 * t]; av1 = ad4[b * 128 + 2 * t + 1]; }
  float4 c0a, c0b, c1a, c1b, c2a, c2b;
  if (hasconv) {
    const float4* c4 = reinterpret_cast<const float4*>(cw);
    c0a = c4[2 * t]; c0b = c4[2 * t + 1];
    c1a = c4[128 + 2 * t]; c1b = c4[128 + 2 * t + 1];
    c2a = c4[256 + 2 * t]; c2b = c4[256 + 2 * t + 1];
  }
  float4 z = make_float4(0.f, 0.f, 0.f, 0.f);
  float4 m2a = z, m2b = z, m1a = z, m1b = z;
  int nrows = hasconv ? 10 : 8;
  int lstart = hasconv ? l0 - 2 : l0;
  for (int j = 0; j < nrows; ++j) {
    int l = lstart + j;
    float4 oa = z, ob = z;
    if (l >= 0) {
      size_t r4 = ((size_t)(b * L_ + l)) * 128;
      float4 v0 = in4[r4 + 2 * t], v1 = in4[r4 + 2 * t + 1];
      float4 a0, a1;
      if (addfull) { a0 = ad4[r4 + 2 * t]; a1 = ad4[r4 + 2 * t + 1]; }
      else { a0 = av0; a1 = av1; }
      v0.x += a0.x; v0.y += a0.y; v0.z += a0.z; v0.w += a0.w;
      v1.x += a1.x; v1.y += a1.y; v1.z += a1.z; v1.w += a1.w;
      float sx = v0.x + v0.y + v0.z + v0.w + v1.x + v1.y + v1.z + v1.w;
      float sq = v0.x * v0.x + v0.y * v0.y + v0.z * v0.z + v0.w * v0.w +
                 v1.x * v1.x + v1.y * v1.y + v1.z * v1.z + v1.w * v1.w;
#pragma unroll
      for (int off = 1; off < 64; off <<= 1) {
        sx += __shfl_xor(sx, off);
        sq += __shfl_xor(sq, off);
      }
      float mu = sx * (1.f / D_);
      float var = sq * (1.f / D_) - mu * mu;
      float rstd = rsqrtf(var + EPS_);
      oa.x = (v0.x - mu) * rstd * g0.x + be0.x;
      oa.y = (v0.y - mu) * rstd * g0.y + be0.y;
      oa.z = (v0.z - mu) * rstd * g0.z + be0.z;
      oa.w = (v0.w - mu) * rstd * g0.w + be0.w;
      ob.x = (v1.x - mu) * rstd * g1.x + be1.x;
      ob.y = (v1.y - mu) * rstd * g1.y + be1.y;
      ob.z = (v1.z - mu) * rstd * g1.z + be1.z;
      ob.w = (v1.w - mu) * rstd * g1.w + be1.w;
      if (l >= l0) {
        out4[r4 + 2 * t] = oa;
        out4[r4 + 2 * t + 1] = ob;
        if (sbf) {
          s16x8 sb;
          sb[0] = (short)f2b(oa.x); sb[1] = (short)f2b(oa.y);
          sb[2] = (short)f2b(oa.z); sb[3] = (short)f2b(oa.w);
          sb[4] = (short)f2b(ob.x); sb[5] = (short)f2b(ob.y);
          sb[6] = (short)f2b(ob.z); sb[7] = (short)f2b(ob.w);
          *reinterpret_cast<s16x8*>(sbf + ((size_t)(b * L_ + l)) * 512 + t * 8) = sb;
        }
      }
    }
    if (hasconv && j >= 2) {
      // conv output row = l (uses ln rows l-2, l-1, l)
      float y0 = c0a.x * m2a.x + c1a.x * m1a.x + c2a.x * oa.x;
      float y1 = c0a.y * m2a.y + c1a.y * m1a.y + c2a.y * oa.y;
      float y2 = c0a.z * m2a.z + c1a.z * m1a.z + c2a.z * oa.z;
      float y3 = c0a.w * m2a.w + c1a.w * m1a.w + c2a.w * oa.w;
      float y4 = c0b.x * m2b.x + c1b.x * m1b.x + c2b.x * ob.x;
      float y5 = c0b.y * m2b.y + c1b.y * m1b.y + c2b.y * ob.y;
      float y6 = c0b.z * m2b.z + c1b.z * m1b.z + c2b.z * ob.z;
      float y7 = c0b.w * m2b.w + c1b.w * m1b.w + c2b.w * ob.w;
      s16x8 xo;
      xo[0] = (short)f2b(silu(y0)); xo[1] = (short)f2b(silu(y1));
      xo[2] = (short)f2b(silu(y2)); xo[3] = (short)f2b(silu(y3));
      xo[4] = (short)f2b(silu(y4)); xo[5] = (short)f2b(silu(y5));
      xo[6] = (short)f2b(silu(y6)); xo[7] = (short)f2b(silu(y7));
      *reinterpret_cast<s16x8*>(xbf + ((size_t)(b * L_ + l)) * 512 + t * 8) = xo;
    }
    m2a = m1a; m2b = m1b; m1a = oa; m1b = ob;
  }
}

// ---------- 128x128 bf16 MFMA GEMM core (reg-staged, single-buffered) ----------
__device__ __forceinline__ void g128_core(const unsigned short* __restrict__ A,
                                          const unsigned short* __restrict__ Bt,
                                          int K, int m0, int n0,
                                          unsigned short* As, unsigned short* Bs,
                                          f32x4 (&acc)[4][4]) {
  int t = threadIdx.x;
  int lane = t & 63;
  int g = lane >> 4, mr = lane & 15;
  int wid = t >> 6, wr = wid >> 1, wc = wid & 1;
#pragma unroll
  for (int i = 0; i < 4; ++i)
#pragma unroll
    for (int j = 0; j < 4; ++j) { f32x4 z = {0.f, 0.f, 0.f, 0.f}; acc[i][j] = z; }
  int r0 = t >> 2, p = (t & 3) * 8;
  const unsigned short* ag0 = A + (size_t)(m0 + r0) * K + p;
  const unsigned short* ag1 = A + (size_t)(m0 + r0 + 64) * K + p;
  const unsigned short* bg0 = Bt + (size_t)(n0 + r0) * K + p;
  const unsigned short* bg1 = Bt + (size_t)(n0 + r0 + 64) * K + p;
  for (int k0 = 0; k0 < K; k0 += 32) {
    s16x8 a0 = *reinterpret_cast<const s16x8*>(ag0 + k0);
    s16x8 a1 = *reinterpret_cast<const s16x8*>(ag1 + k0);
    s16x8 b0 = *reinterpret_cast<const s16x8*>(bg0 + k0);
    s16x8 b1 = *reinterpret_cast<const s16x8*>(bg1 + k0);
    __syncthreads();
    *reinterpret_cast<s16x8*>(As + (size_t)t * 8) = a0;
    *reinterpret_cast<s16x8*>(As + (size_t)(t + 256) * 8) = a1;
    *reinterpret_cast<s16x8*>(Bs + (size_t)t * 8) = b0;
    *reinterpret_cast<s16x8*>(Bs + (size_t)(t + 256) * 8) = b1;
    __syncthreads();
    s16x8 af[4], bf[4];
#pragma unroll
    for (int fm = 0; fm < 4; ++fm)
      af[fm] = *reinterpret_cast<const s16x8*>(As + (size_t)(wr * 64 + fm * 16 + mr) * 32 + g * 8);
#pragma unroll
    for (int fn = 0; fn < 4; ++fn)
      bf[fn] = *reinterpret_cast<const s16x8*>(Bs + (size_t)(wc * 64 + fn * 16 + mr) * 32 + g * 8);
#pragma unroll
    for (int fm = 0; fm < 4; ++fm)
#pragma unroll
      for (int fn = 0; fn < 4; ++fn)
        acc[fm][fn] = __builtin_amdgcn_mfma_f32_16x16x32_bf16(af[fm], bf[fn], acc[fm][fn], 0, 0, 0);
  }
}

// ---------- plain C = A*Bt^T (+bias), f32 out ----------
__global__ __launch_bounds__(256) void k_g128(const unsigned short* __restrict__ A,
                                              const unsigned short* __restrict__ Bt,
                                              float* __restrict__ C,
                                              const float* __restrict__ bias,
                                              int N, int K) {
  __shared__ __align__(16) unsigned short As[4096], Bs[4096];
  int m0 = blockIdx.x * 128, n0 = blockIdx.y * 128;
  f32x4 acc[4][4];
  g128_core(A, Bt, K, m0, n0, As, Bs, acc);
  int t = threadIdx.x, lane = t & 63, g = lane >> 4, mr = lane & 15;
  int wid = t >> 6, wr = wid >> 1, wc = wid & 1;
#pragma unroll
  for (int fm = 0; fm < 4; ++fm)
#pragma unroll
    for (int fn = 0; fn < 4; ++fn) {
      int row = m0 + wr * 64 + fm * 16 + g * 4;
      int col = n0 + wc * 64 + fn * 16 + mr;
      float badd = bias ? bias[col] : 0.f;
#pragma unroll
      for (int q = 0; q < 4; ++q)
        C[(size_t)(row + q) * N + col] = acc[fm][fn][q] + badd;
    }
}

// ---------- QKV GEMM: Q(scaled)/K -> [B,H,L,64]; V -> transposed [B,H,64,L] ----------
__global__ __launch_bounds__(256) void k_g128_qkv(const unsigned short* __restrict__ A,
                                                  const unsigned short* __restrict__ Bt,
                                                  const float* __restrict__ bias,
                                                  unsigned short* __restrict__ Qbf,
                                                  unsigned short* __restrict__ Kbf,
                                                  unsigned short* __restrict__ VbfT) {
  __shared__ __align__(16) unsigned short sm[8192];
  int m0 = blockIdx.x * 128, n0 = blockIdx.y * 128;
  f32x4 acc[4][4];
  g128_core(A, Bt, 512, m0, n0, sm, sm + 4096, acc);
  int t = threadIdx.x, lane = t & 63, g = lane >> 4, mr = lane & 15;
  int wid = t >> 6, wr = wid >> 1, wc = wid & 1;
  int b = m0 >> 11, l0 = m0 & (L_ - 1);
  if (n0 < 1024) {
    // Q / K sections: head-major [B,H,L,64]
#pragma unroll
    for (int fm = 0; fm < 4; ++fm)
#pragma unroll
      for (int fn = 0; fn < 4; ++fn) {
        int row0 = m0 + wr * 64 + fm * 16 + g * 4;
        int col = n0 + wc * 64 + fn * 16 + mr;
        int sec = col >> 9;           // 0=Q 1=K
        int hh = (col >> 6) & 7;
        int dh = col & 63;
        float badd = bias[col];
        float scale = (sec == 0) ? 0.125f : 1.f;
        unsigned short* dstbase = (sec == 0) ? Qbf : Kbf;
#pragma unroll
        for (int q = 0; q < 4; ++q) {
          int row = row0 + q;
          int bb = row >> 11, l = row & (L_ - 1);
          dstbase[(((size_t)(bb * H_ + hh)) * L_ + l) * 64 + dh] =
              f2b((acc[fm][fn][q] + badd) * scale);
        }
      }
  } else {
    // V section: transpose through LDS -> [B,H,64(dh),L]
#pragma unroll
    for (int chalf = 0; chalf < 2; ++chalf) {
      __syncthreads();
      if (wc == chalf) {
#pragma unroll
        for (int fm = 0; fm < 4; ++fm)
#pragma unroll
          for (int fn = 0; fn < 4; ++fn) {
            int col = n0 + wc * 64 + fn * 16 + mr;
            float badd = bias[col];
            int col_local = fn * 16 + mr;
            int row_local = wr * 64 + fm * 16 + g * 4;
            ushort4 pk;
            pk.x = f2b(acc[fm][fn][0] + badd);
            pk.y = f2b(acc[fm][fn][1] + badd);
            pk.z = f2b(acc[fm][fn][2] + badd);
            pk.w = f2b(acc[fm][fn][3] + badd);
            *reinterpret_cast<ushort4*>(&sm[col_local * 128 + row_local]) = pk;
          }
      }
      __syncthreads();
      int c = t >> 2, lp = (t & 3) * 32;
      int h = ((n0 - 1024) >> 6) + chalf;
      unsigned short* dst = VbfT + (((size_t)(b * H_ + h)) * 64 + c) * L_ + l0 + lp;
#pragma unroll
      for (int u = 0; u < 4; ++u)
        *reinterpret_cast<s16x8*>(dst + u * 8) =
            *reinterpret_cast<const s16x8*>(&sm[c * 128 + lp + u * 8]);
    }
  }
}

// ---------- u GEMM with fused decay-weighted row reduction ----------
__global__ __launch_bounds__(256) void k_g128_u(const unsigned short* __restrict__ A,
                                                const unsigned short* __restrict__ Bt,
                                                const float* __restrict__ Ap,
                                                float* __restrict__ part2) {
  __shared__ __align__(16) unsigned short As[4096], Bs[4096];
  int m0 = blockIdx.x * 128, n0 = blockIdx.y * 128;
  f32x4 acc[4][4];
  g128_core(A, Bt, 512, m0, n0, As, Bs, acc);
  int t = threadIdx.x, lane = t & 63, g = lane >> 4, mr = lane & 15;
  int wid = t >> 6, wr = wid >> 1, wc = wid & 1;
  int b = m0 >> 11, mchunk = (m0 >> 7) & 15;
  float wsum[4];
#pragma unroll
  for (int fn = 0; fn < 4; ++fn) {
    int col = n0 + wc * 64 + fn * 16 + mr;
    float a = 1.f / (1.f + expf(-Ap[col]));
    float la2 = log2f(a);
    float s = 0.f;
#pragma unroll
    for (int fm = 0; fm < 4; ++fm) {
      int rbase = (m0 + wr * 64 + fm * 16 + g * 4) & (L_ - 1);
#pragma unroll
      for (int q = 0; q < 4; ++q) {
        float e = (float)(2047 - (rbase + q));
        s += acc[fm][fn][q] * exp2f(e * la2);
      }
    }
    s += __shfl_xor(s, 16);
    s += __shfl_xor(s, 32);
    wsum[fn] = s;
  }
  float* red = (float*)As;
  __syncthreads();
  if (wr == 0 && g == 0) {
#pragma unroll
    for (int fn = 0; fn < 4; ++fn) red[(wc * 4 + fn) * 16 + mr] = wsum[fn];
  }
  __syncthreads();
  if (wr == 1 && g == 0) {
#pragma unroll
    for (int fn = 0; fn < 4; ++fn) {
      int col = n0 + wc * 64 + fn * 16 + mr;
      part2[(size_t)(b * 16 + mchunk) * 256 + col] =
          wsum[fn] + red[(wc * 4 + fn) * 16 + mr];
    }
  }
}

// ---------- fused mamba tail ----------
__global__ __launch_bounds__(256) void k_tail(float* __restrict__ state,
                                              const float* __restrict__ Wh,
                                              const float* __restrict__ Wout,
                                              const float* __restrict__ Ap,
                                              const float* __restrict__ part2,
                                              int use_h0) {
  int b = blockIdx.x, t = threadIdx.x;
  __shared__ float sst[512];
  __shared__ float hTs[256];
  float h0v = 0.f;
  if (use_h0) {
    sst[t] = state[b * 512 + t];
    sst[t + 256] = state[b * 512 + t + 256];
    __syncthreads();
    for (int d = 0; d < 512; ++d) h0v += sst[d] * Wh[(size_t)d * 256 + t];
  }
  float acc = 0.f;
  for (int c = 0; c < 16; ++c) acc += part2[(size_t)(b * 16 + c) * 256 + t];
  if (use_h0) {
    float a = 1.f / (1.f + expf(-Ap[t]));
    acc += exp2f(2048.f * log2f(a)) * h0v;
  }
  hTs[t] = acc;
  __syncthreads();
#pragma unroll
  for (int r = 0; r < 2; ++r) {
    int d = r * 256 + t;
    float s = 0.f;
    for (int ss = 0; ss < 256; ++ss) s += hTs[ss] * Wout[(size_t)ss * 512 + d];
    state[b * 512 + d] = s;
  }
}

// ---------- flash banded attention (no-max softmax, deferred sum) ----------
// Q/K [B,H,L,64]; V transposed [B,H,64,L]; out attnbf [B,L,512]
__global__ __launch_bounds__(256) void k_fattn(const unsigned short* __restrict__ Qbf,
                                               const unsigned short* __restrict__ Kbf,
                                               const unsigned short* __restrict__ VbfT,
                                               unsigned short* __restrict__ attnbf) {
  __shared__ __align__(16) unsigned short Ks[64][72];
  __shared__ __align__(16) unsigned short Vt[64][72];
  __shared__ __align__(16) unsigned short Ps[4][16][72];
  int b = blockIdx.z, h = blockIdx.y, q0 = blockIdx.x * 64;
  int t = threadIdx.x;
  int lane = t & 63, wid = t >> 6;
  int g = lane >> 4, mr = lane & 15;
  const unsigned short* Qp = Qbf + ((size_t)(b * H_ + h)) * L_ * 64;
  const unsigned short* Kp = Kbf + ((size_t)(b * H_ + h)) * L_ * 64;
  const unsigned short* VpT = VbfT + ((size_t)(b * H_ + h)) * 64 * L_;
  int qbase = q0 + wid * 16;
  s16x8 qf0 = *reinterpret_cast<const s16x8*>(Qp + (size_t)(qbase + mr) * 64 + g * 8);
  s16x8 qf1 = *reinterpret_cast<const s16x8*>(Qp + (size_t)(qbase + mr) * 64 + 32 + g * 8);
  f32x4 oacc[4];
#pragma unroll
  for (int fn = 0; fn < 4; ++fn) { f32x4 zz = {0.f, 0.f, 0.f, 0.f}; oacc[fn] = zz; }
  float lsum[4] = {0.f, 0.f, 0.f, 0.f};
  int kstart = q0 - WIN_; if (kstart < 0) kstart = 0;
  int kend = q0 + 64 + WIN_; if (kend > L_) kend = L_;

  for (int kt = kstart; kt < kend; kt += 64) {
    __syncthreads();
#pragma unroll
    for (int it = 0; it < 2; ++it) {
      int chunk = t + it * 256;
      int row = chunk >> 3, c8 = (chunk & 7) * 8;
      *reinterpret_cast<s16x8*>(&Ks[row][c8]) =
          *reinterpret_cast<const s16x8*>(Kp + (size_t)(kt + row) * 64 + c8);
      *reinterpret_cast<s16x8*>(&Vt[row][c8]) =
          *reinterpret_cast<const s16x8*>(VpT + (size_t)row * L_ + kt + c8);
    }
    __syncthreads();
    f32x4 sacc[4];
#pragma unroll
    for (int n = 0; n < 4; ++n) {
      f32x4 zz = {0.f, 0.f, 0.f, 0.f};
      sacc[n] = zz;
      s16x8 kf0 = *reinterpret_cast<const s16x8*>(&Ks[n * 16 + mr][g * 8]);
      s16x8 kf1 = *reinterpret_cast<const s16x8*>(&Ks[n * 16 + mr][32 + g * 8]);
      sacc[n] = __builtin_amdgcn_mfma_f32_16x16x32_bf16(qf0, kf0, sacc[n], 0, 0, 0);
      sacc[n] = __builtin_amdgcn_mfma_f32_16x16x32_bf16(qf1, kf1, sacc[n], 0, 0, 0);
    }
    // scores are data-bounded (|s| << 80): exp without max subtraction is exact in f32.
    bool needmask = (kt - q0 > 192) || (q0 - kt > 192);
#pragma unroll
    for (int reg = 0; reg < 4; ++reg) {
      int q_abs = qbase + g * 4 + reg;
#pragma unroll
      for (int n = 0; n < 4; ++n) {
        float pv = exp2f(sacc[n][reg] * LOG2E_);
        if (needmask) {
          int key = kt + n * 16 + mr;
          int dd = key - q_abs; dd = dd < 0 ? -dd : dd;
          if (dd > WIN_) pv = 0.f;
        }
        lsum[reg] += pv;
        Ps[wid][g * 4 + reg][n * 16 + mr] = f2b(pv);
      }
    }
    s16x8 pa0 = *reinterpret_cast<const s16x8*>(&Ps[wid][mr][g * 8]);
    s16x8 pa1 = *reinterpret_cast<const s16x8*>(&Ps[wid][mr][32 + g * 8]);
#pragma unroll
    for (int fn = 0; fn < 4; ++fn) {
      s16x8 vf0 = *reinterpret_cast<const s16x8*>(&Vt[fn * 16 + mr][g * 8]);
      s16x8 vf1 = *reinterpret_cast<const s16x8*>(&Vt[fn * 16 + mr][32 + g * 8]);
      oacc[fn] = __builtin_amdgcn_mfma_f32_16x16x32_bf16(pa0, vf0, oacc[fn], 0, 0, 0);
      oacc[fn] = __builtin_amdgcn_mfma_f32_16x16x32_bf16(pa1, vf1, oacc[fn], 0, 0, 0);
    }
  }
#pragma unroll
  for (int reg = 0; reg < 4; ++reg) {
    float ls = lsum[reg];
#pragma unroll
    for (int off = 1; off < 16; off <<= 1) ls += __shfl_xor(ls, off);
    float inv = 1.f / ls;
    int q_abs = qbase + g * 4 + reg;
    unsigned short* dst = attnbf + ((size_t)(b * L_ + q_abs)) * 512 + h * 64;
#pragma unroll
    for (int fn = 0; fn < 4; ++fn)
      dst[fn * 16 + mr] = f2b(oacc[fn][reg] * inv);
  }
}

extern "C" void kernel_launch(void* const* d_in, const int* in_sizes, int n_in,
                              void* d_out, int out_size, void* d_ws, size_t ws_size,
                              hipStream_t stream) {
  const float* context = (const float*)d_in[0];
  const float* conv_w  = (const float*)d_in[1];
  const float* Wx      = (const float*)d_in[2];
  const float* Wh      = (const float*)d_in[3];
  const float* Wout    = (const float*)d_in[4];
  const float* Aparm   = (const float*)d_in[5];
  const float* gamma_m = (const float*)d_in[6];
  const float* beta_m  = (const float*)d_in[7];
  const float* gamma_a = (const float*)d_in[8];
  const float* beta_a  = (const float*)d_in[9];
  const float* Wqkv    = (const float*)d_in[10];
  const float* bqkv    = (const float*)d_in[11];
  const float* Wo      = (const float*)d_in[12];
  const float* bo      = (const float*)d_in[13];
  float* seqA = (float*)d_out;
  float* ws = (float*)d_ws;

  // ws layout (float units). seqB aliases Qbf+Kbf: seqB live F1->F2 and F3->F4;
  // Qbf/Kbf live only QKVgemm->fattn (between F2's read and F3's write). Disjoint.
  float* proj = ws;                                           // 4,194,304
  float* seqB = ws + 4194304;                                 // 4,194,304 (alias Qbf/Kbf)
  unsigned short* Qbf    = (unsigned short*)(ws + 4194304);
  unsigned short* Kbf    = (unsigned short*)(ws + 6291456);
  unsigned short* VbfT   = (unsigned short*)(ws + 8388608);   // [B,H,64,L]
  unsigned short* xbf    = (unsigned short*)(ws + 10485760);
  unsigned short* sbf    = (unsigned short*)(ws + 12582912);  // seq bf16 / attn out bf16
  unsigned short* wqkvbf = (unsigned short*)(ws + 14680064);
  unsigned short* wobf   = (unsigned short*)(ws + 15073280);
  unsigned short* wxtbf  = (unsigned short*)(ws + 15204352);
  float* state = ws + 15597568;                               // 2048
  float* part2 = state + 2048;                                // 16384

  k_f2b<<<768, 256, 0, stream>>>(Wqkv, wqkvbf, 196608);
  k_f2b<<<256, 256, 0, stream>>>(Wo, wobf, 65536);
  k_twx<<<dim3(16, 8, 6), dim3(32, 8), 0, stream>>>(Wx, wxtbf);

  k_conv_silu<<<B_ * L_, 128, 0, stream>>>(context, conv_w, xbf);

  for (int i = 0; i < 6; ++i) {
    k_g128_u<<<dim3(64, 2), 256, 0, stream>>>(xbf, wxtbf + (size_t)i * S_ * D_,
                                              Aparm + (size_t)i * S_, part2);
    k_tail<<<B_, 256, 0, stream>>>(state, Wh + (size_t)i * D_ * S_,
                                   Wout + (size_t)i * S_ * D_,
                                   Aparm + (size_t)i * S_, part2, i > 0 ? 1 : 0);
    const float* cwn = conv_w + (size_t)(i + 1) * 3 * D_;
    switch (i) {
      case 0:  // LN_m(0) + conv(1): context -> A
        k_lnconv<<<1024, 64, 0, stream>>>(context, state, 0, gamma_m, beta_m,
                                          seqA, xbf, cwn, nullptr);
        break;
      case 1:  // A -> B
        k_lnconv<<<1024, 64, 0, stream>>>(seqA, state, 0, gamma_m, beta_m,
                                          seqB, xbf, cwn, nullptr);
        break;
      case 2:  // B -> A
        k_lnconv<<<1024, 64, 0, stream>>>(seqB, state, 0, gamma_m, beta_m,
                                          seqA, xbf, cwn, nullptr);
        break;
      case 3:  // LN_m(3) in-place A + bf16 mirror; attention; LN_a(3)+conv(4): A -> B
        k_lnconv<<<1024, 64, 0, stream>>>(seqA, state, 0, gamma_m, beta_m,
                                          seqA, nullptr, nullptr, sbf);
        k_g128_qkv<<<dim3(64, 12), 256, 0, stream>>>(sbf, wqkvbf, bqkv, Qbf, Kbf, VbfT);
        k_fattn<<<dim3(32, 8, 4), 256, 0, stream>>>(Qbf, Kbf, VbfT, sbf);
        k_g128<<<dim3(64, 4), 256, 0, stream>>>(sbf, wobf, proj, bo, 512, 512);
        k_lnconv<<<1024, 64, 0, stream>>>(seqA, proj, 1, gamma_a, beta_a,
                                          seqB, xbf, cwn, nullptr);
        break;
      case 4:  // B -> A
        k_lnconv<<<1024, 64, 0, stream>>>(seqB, state, 0, gamma_m, beta_m,
                                          seqA, xbf, cwn, nullptr);
        break;
      case 5:  // final LN_m(5) in-place in d_out
        k_lnconv<<<1024, 64, 0, stream>>>(seqA, state, 0, gamma_m, beta_m,
                                          seqA, nullptr, nullptr, nullptr);
        break;
    }
  }
}

// Round 5
// 299.707 us; speedup vs baseline: 13.3955x; 1.5157x over previous
//
#include <hip/hip_runtime.h>

#define B_ 4
#define L_ 2048
#define D_ 512
#define S_ 256
#define H_ 8
#define DH_ 64
#define WIN_ 256
#define EPS_ 1e-5f
#define LOG2E_ 1.4426950408889634f

using f32x4 = __attribute__((ext_vector_type(4))) float;
using s16x8 = __attribute__((ext_vector_type(8))) short;

__device__ __forceinline__ unsigned short f2b(float f) {
  unsigned int u = __builtin_bit_cast(unsigned int, f);
  u += 0x7FFFu + ((u >> 16) & 1u);   // RNE to bf16 (inputs finite)
  return (unsigned short)(u >> 16);
}

__device__ __forceinline__ float silu(float y) { return y / (1.f + expf(-y)); }

// async global->LDS 16B DMA: lds dest is wave-uniform base, HW adds lane*16.
__device__ __forceinline__ void gll16(const void* g, void* l) {
  __builtin_amdgcn_global_load_lds((const __attribute__((address_space(1))) void*)g,
                                   (__attribute__((address_space(3))) void*)l, 16, 0, 0);
}

// ---------- f32 -> bf16 convert (n4 = n/4) ----------
__global__ __launch_bounds__(256) void k_f2b(const float* __restrict__ in,
                                             unsigned short* __restrict__ out, int n4) {
  int i = blockIdx.x * 256 + threadIdx.x;
  if (i >= n4) return;
  float4 v = reinterpret_cast<const float4*>(in)[i];
  ushort4 o;
  o.x = f2b(v.x); o.y = f2b(v.y); o.z = f2b(v.z); o.w = f2b(v.w);
  reinterpret_cast<ushort4*>(out)[i] = o;
}

// ---------- transpose+convert Wx (NL,D,S) -> (NL,S,D) bf16 ----------
__global__ void k_twx(const float* __restrict__ wx, unsigned short* __restrict__ wxt) {
  __shared__ float tile[32][33];
  int lyr = blockIdx.z;
  int d0 = blockIdx.x * 32, s0 = blockIdx.y * 32;
  const float* src = wx + (size_t)lyr * D_ * S_;
  unsigned short* dst = wxt + (size_t)lyr * S_ * D_;
  for (int r = threadIdx.y; r < 32; r += 8)
    tile[r][threadIdx.x] = src[(size_t)(d0 + r) * S_ + s0 + threadIdx.x];
  __syncthreads();
  for (int r = threadIdx.y; r < 32; r += 8)
    dst[(size_t)(s0 + r) * D_ + d0 + threadIdx.x] = f2b(tile[threadIdx.x][r]);
}

// ---------- causal depthwise conv (k=3) + SiLU, layer-0 (reads context) ----------
__global__ __launch_bounds__(128) void k_conv_silu(const float* __restrict__ seq,
                                                   const float* __restrict__ cw,
                                                   unsigned short* __restrict__ x) {
  int bl = blockIdx.x;
  int l = bl & (L_ - 1);
  int t = threadIdx.x;
  const float4* s4 = reinterpret_cast<const float4*>(seq);
  const float4* c4 = reinterpret_cast<const float4*>(cw);
  size_t row = (size_t)bl * 128;
  float4 c0 = c4[t], c1 = c4[128 + t], c2 = c4[256 + t];
  float4 z = make_float4(0.f, 0.f, 0.f, 0.f);
  float4 s0 = (l >= 2) ? s4[row - 256 + t] : z;
  float4 s1 = (l >= 1) ? s4[row - 128 + t] : z;
  float4 s2 = s4[row + t];
  float y0 = c0.x * s0.x + c1.x * s1.x + c2.x * s2.x;
  float y1 = c0.y * s0.y + c1.y * s1.y + c2.y * s2.y;
  float y2 = c0.z * s0.z + c1.z * s1.z + c2.z * s2.z;
  float y3 = c0.w * s0.w + c1.w * s1.w + c2.w * s2.w;
  ushort4 o;
  o.x = f2b(silu(y0)); o.y = f2b(silu(y1)); o.z = f2b(silu(y2)); o.w = f2b(silu(y3));
  reinterpret_cast<ushort4*>(x)[row + t] = o;
}

// ---------- fused LayerNorm(seqIn + add) -> seqOut [+bf16 mirror] [+conv(k=3)+SiLU -> xbf] ----------
__global__ __launch_bounds__(64) void k_lnconv(const float* __restrict__ seqIn,
                                               const float* __restrict__ add, int addfull,
                                               const float* __restrict__ gamma,
                                               const float* __restrict__ beta,
                                               float* __restrict__ seqOut,
                                               unsigned short* __restrict__ xbf,
                                               const float* __restrict__ cw,
                                               unsigned short* __restrict__ sbf) {
  int t = threadIdx.x;
  int r0 = blockIdx.x * 8;
  int b = r0 >> 11, l0 = r0 & (L_ - 1);
  bool hasconv = (cw != nullptr);
  const float4* in4 = reinterpret_cast<const float4*>(seqIn);
  const float4* ad4 = reinterpret_cast<const float4*>(add);
  float4* out4 = reinterpret_cast<float4*>(seqOut);
  float4 g0 = reinterpret_cast<const float4*>(gamma)[2 * t];
  float4 g1 = reinterpret_cast<const float4*>(gamma)[2 * t + 1];
  float4 be0 = reinterpret_cast<const float4*>(beta)[2 * t];
  float4 be1 = reinterpret_cast<const float4*>(beta)[2 * t + 1];
  float4 av0, av1;
  if (!addfull) { av0 = ad4[b * 128 + 2 * t]; av1 = ad4[b * 128 + 2 * t + 1]; }
  float4 c0a, c0b, c1a, c1b, c2a, c2b;
  if (hasconv) {
    const float4* c4 = reinterpret_cast<const float4*>(cw);
    c0a = c4[2 * t]; c0b = c4[2 * t + 1];
    c1a = c4[128 + 2 * t]; c1b = c4[128 + 2 * t + 1];
    c2a = c4[256 + 2 * t]; c2b = c4[256 + 2 * t + 1];
  }
  float4 z = make_float4(0.f, 0.f, 0.f, 0.f);
  float4 m2a = z, m2b = z, m1a = z, m1b = z;
  int nrows = hasconv ? 10 : 8;
  int lstart = hasconv ? l0 - 2 : l0;
  for (int j = 0; j < nrows; ++j) {
    int l = lstart + j;
    float4 oa = z, ob = z;
    if (l >= 0) {
      size_t r4 = ((size_t)(b * L_ + l)) * 128;
      float4 v0 = in4[r4 + 2 * t], v1 = in4[r4 + 2 * t + 1];
      float4 a0, a1;
      if (addfull) { a0 = ad4[r4 + 2 * t]; a1 = ad4[r4 + 2 * t + 1]; }
      else { a0 = av0; a1 = av1; }
      v0.x += a0.x; v0.y += a0.y; v0.z += a0.z; v0.w += a0.w;
      v1.x += a1.x; v1.y += a1.y; v1.z += a1.z; v1.w += a1.w;
      float sx = v0.x + v0.y + v0.z + v0.w + v1.x + v1.y + v1.z + v1.w;
      float sq = v0.x * v0.x + v0.y * v0.y + v0.z * v0.z + v0.w * v0.w +
                 v1.x * v1.x + v1.y * v1.y + v1.z * v1.z + v1.w * v1.w;
#pragma unroll
      for (int off = 1; off < 64; off <<= 1) {
        sx += __shfl_xor(sx, off);
        sq += __shfl_xor(sq, off);
      }
      float mu = sx * (1.f / D_);
      float var = sq * (1.f / D_) - mu * mu;
      float rstd = rsqrtf(var + EPS_);
      oa.x = (v0.x - mu) * rstd * g0.x + be0.x;
      oa.y = (v0.y - mu) * rstd * g0.y + be0.y;
      oa.z = (v0.z - mu) * rstd * g0.z + be0.z;
      oa.w = (v0.w - mu) * rstd * g0.w + be0.w;
      ob.x = (v1.x - mu) * rstd * g1.x + be1.x;
      ob.y = (v1.y - mu) * rstd * g1.y + be1.y;
      ob.z = (v1.z - mu) * rstd * g1.z + be1.z;
      ob.w = (v1.w - mu) * rstd * g1.w + be1.w;
      if (l >= l0) {
        out4[r4 + 2 * t] = oa;
        out4[r4 + 2 * t + 1] = ob;
        if (sbf) {
          s16x8 sb;
          sb[0] = (short)f2b(oa.x); sb[1] = (short)f2b(oa.y);
          sb[2] = (short)f2b(oa.z); sb[3] = (short)f2b(oa.w);
          sb[4] = (short)f2b(ob.x); sb[5] = (short)f2b(ob.y);
          sb[6] = (short)f2b(ob.z); sb[7] = (short)f2b(ob.w);
          *reinterpret_cast<s16x8*>(sbf + ((size_t)(b * L_ + l)) * 512 + t * 8) = sb;
        }
      }
    }
    if (hasconv && j >= 2) {
      float y0 = c0a.x * m2a.x + c1a.x * m1a.x + c2a.x * oa.x;
      float y1 = c0a.y * m2a.y + c1a.y * m1a.y + c2a.y * oa.y;
      float y2 = c0a.z * m2a.z + c1a.z * m1a.z + c2a.z * oa.z;
      float y3 = c0a.w * m2a.w + c1a.w * m1a.w + c2a.w * oa.w;
      float y4 = c0b.x * m2b.x + c1b.x * m1b.x + c2b.x * ob.x;
      float y5 = c0b.y * m2b.y + c1b.y * m1b.y + c2b.y * ob.y;
      float y6 = c0b.z * m2b.z + c1b.z * m1b.z + c2b.z * ob.z;
      float y7 = c0b.w * m2b.w + c1b.w * m1b.w + c2b.w * ob.w;
      s16x8 xo;
      xo[0] = (short)f2b(silu(y0)); xo[1] = (short)f2b(silu(y1));
      xo[2] = (short)f2b(silu(y2)); xo[3] = (short)f2b(silu(y3));
      xo[4] = (short)f2b(silu(y4)); xo[5] = (short)f2b(silu(y5));
      xo[6] = (short)f2b(silu(y6)); xo[7] = (short)f2b(silu(y7));
      *reinterpret_cast<s16x8*>(xbf + ((size_t)(b * L_ + l)) * 512 + t * 8) = xo;
    }
    m2a = m1a; m2b = m1b; m1a = oa; m1b = ob;
  }
}

// ---------- 128x128 bf16 MFMA GEMM core (global_load_lds staged, m97 structure) ----------
// Staging layout is linear in thread id: lane l of wave w -> LDS byte (w*64+l)*16,
// exactly the HW's wave-uniform-base + lane*16 rule. Per-lane global src address.
__device__ __forceinline__ void g128_core(const unsigned short* __restrict__ A,
                                          const unsigned short* __restrict__ Bt,
                                          int K, int m0, int n0, int k_lo, int k_hi,
                                          unsigned short* As, unsigned short* Bs,
                                          f32x4 (&acc)[4][4]) {
  int t = threadIdx.x;
  int lane = t & 63;
  int g = lane >> 4, mr = lane & 15;
  int wid = t >> 6, wr = wid >> 1, wc = wid & 1;
#pragma unroll
  for (int i = 0; i < 4; ++i)
#pragma unroll
    for (int j = 0; j < 4; ++j) { f32x4 z = {0.f, 0.f, 0.f, 0.f}; acc[i][j] = z; }
  int r0 = t >> 2, p = (t & 3) * 8;
  const unsigned short* ag0 = A + (size_t)(m0 + r0) * K + p;
  const unsigned short* ag1 = ag0 + (size_t)64 * K;
  const unsigned short* bg0 = Bt + (size_t)(n0 + r0) * K + p;
  const unsigned short* bg1 = bg0 + (size_t)64 * K;
  unsigned short* Asw0 = As + wid * 512;
  unsigned short* Asw1 = As + 2048 + wid * 512;
  unsigned short* Bsw0 = Bs + wid * 512;
  unsigned short* Bsw1 = Bs + 2048 + wid * 512;
  for (int k0 = k_lo; k0 < k_hi; k0 += 32) {
    __syncthreads();                 // previous tile's ds_reads done
    gll16(ag0 + k0, Asw0);
    gll16(ag1 + k0, Asw1);
    gll16(bg0 + k0, Bsw0);
    gll16(bg1 + k0, Bsw1);
    __syncthreads();                 // vmcnt(0) drain -> tile ready
    s16x8 af[4], bf[4];
#pragma unroll
    for (int fm = 0; fm < 4; ++fm)
      af[fm] = *reinterpret_cast<const s16x8*>(As + (size_t)(wr * 64 + fm * 16 + mr) * 32 + g * 8);
#pragma unroll
    for (int fn = 0; fn < 4; ++fn)
      bf[fn] = *reinterpret_cast<const s16x8*>(Bs + (size_t)(wc * 64 + fn * 16 + mr) * 32 + g * 8);
#pragma unroll
    for (int fm = 0; fm < 4; ++fm)
#pragma unroll
      for (int fn = 0; fn < 4; ++fn)
        acc[fm][fn] = __builtin_amdgcn_mfma_f32_16x16x32_bf16(af[fm], bf[fn], acc[fm][fn], 0, 0, 0);
  }
}

// ---------- plain C = A*Bt^T (+bias), f32 out ----------
__global__ __launch_bounds__(256) void k_g128(const unsigned short* __restrict__ A,
                                              const unsigned short* __restrict__ Bt,
                                              float* __restrict__ C,
                                              const float* __restrict__ bias,
                                              int N, int K) {
  __shared__ __align__(16) unsigned short As[4096], Bs[4096];
  int m0 = blockIdx.x * 128, n0 = blockIdx.y * 128;
  f32x4 acc[4][4];
  g128_core(A, Bt, K, m0, n0, 0, K, As, Bs, acc);
  int t = threadIdx.x, lane = t & 63, g = lane >> 4, mr = lane & 15;
  int wid = t >> 6, wr = wid >> 1, wc = wid & 1;
#pragma unroll
  for (int fm = 0; fm < 4; ++fm)
#pragma unroll
    for (int fn = 0; fn < 4; ++fn) {
      int row = m0 + wr * 64 + fm * 16 + g * 4;
      int col = n0 + wc * 64 + fn * 16 + mr;
      float badd = bias ? bias[col] : 0.f;
#pragma unroll
      for (int q = 0; q < 4; ++q)
        C[(size_t)(row + q) * N + col] = acc[fm][fn][q] + badd;
    }
}

// ---------- QKV GEMM: Q(scaled)/K -> [B,H,L,64]; V -> transposed [B,H,64,L] ----------
__global__ __launch_bounds__(256) void k_g128_qkv(const unsigned short* __restrict__ A,
                                                  const unsigned short* __restrict__ Bt,
                                                  const float* __restrict__ bias,
                                                  unsigned short* __restrict__ Qbf,
                                                  unsigned short* __restrict__ Kbf,
                                                  unsigned short* __restrict__ VbfT) {
  __shared__ __align__(16) unsigned short sm[8192];
  int m0 = blockIdx.x * 128, n0 = blockIdx.y * 128;
  f32x4 acc[4][4];
  g128_core(A, Bt, 512, m0, n0, 0, 512, sm, sm + 4096, acc);
  int t = threadIdx.x, lane = t & 63, g = lane >> 4, mr = lane & 15;
  int wid = t >> 6, wr = wid >> 1, wc = wid & 1;
  int b = m0 >> 11, l0 = m0 & (L_ - 1);
  if (n0 < 1024) {
#pragma unroll
    for (int fm = 0; fm < 4; ++fm)
#pragma unroll
      for (int fn = 0; fn < 4; ++fn) {
        int row0 = m0 + wr * 64 + fm * 16 + g * 4;
        int col = n0 + wc * 64 + fn * 16 + mr;
        int sec = col >> 9;           // 0=Q 1=K
        int hh = (col >> 6) & 7;
        int dh = col & 63;
        float badd = bias[col];
        float scale = (sec == 0) ? 0.125f : 1.f;
        unsigned short* dstbase = (sec == 0) ? Qbf : Kbf;
#pragma unroll
        for (int q = 0; q < 4; ++q) {
          int row = row0 + q;
          int bb = row >> 11, l = row & (L_ - 1);
          dstbase[(((size_t)(bb * H_ + hh)) * L_ + l) * 64 + dh] =
              f2b((acc[fm][fn][q] + badd) * scale);
        }
      }
  } else {
#pragma unroll
    for (int chalf = 0; chalf < 2; ++chalf) {
      __syncthreads();
      if (wc == chalf) {
#pragma unroll
        for (int fm = 0; fm < 4; ++fm)
#pragma unroll
          for (int fn = 0; fn < 4; ++fn) {
            int col = n0 + wc * 64 + fn * 16 + mr;
            float badd = bias[col];
            int col_local = fn * 16 + mr;
            int row_local = wr * 64 + fm * 16 + g * 4;
            ushort4 pk;
            pk.x = f2b(acc[fm][fn][0] + badd);
            pk.y = f2b(acc[fm][fn][1] + badd);
            pk.z = f2b(acc[fm][fn][2] + badd);
            pk.w = f2b(acc[fm][fn][3] + badd);
            *reinterpret_cast<ushort4*>(&sm[col_local * 128 + row_local]) = pk;
          }
      }
      __syncthreads();
      int c = t >> 2, lp = (t & 3) * 32;
      int h = ((n0 - 1024) >> 6) + chalf;
      unsigned short* dst = VbfT + (((size_t)(b * H_ + h)) * 64 + c) * L_ + l0 + lp;
#pragma unroll
      for (int u = 0; u < 4; ++u)
        *reinterpret_cast<s16x8*>(dst + u * 8) =
            *reinterpret_cast<const s16x8*>(&sm[c * 128 + lp + u * 8]);
    }
  }
}

// ---------- u GEMM (split-K over blockIdx.z) with fused decay-weighted row reduction ----------
// part3[((b*16+mchunk)*4 + kz)*256 + s]
__global__ __launch_bounds__(256) void k_g128_u(const unsigned short* __restrict__ A,
                                                const unsigned short* __restrict__ Bt,
                                                const float* __restrict__ Ap,
                                                float* __restrict__ part3) {
  __shared__ __align__(16) unsigned short As[4096], Bs[4096];
  int m0 = blockIdx.x * 128, n0 = blockIdx.y * 128;
  int kz = blockIdx.z;
  f32x4 acc[4][4];
  g128_core(A, Bt, 512, m0, n0, kz * 128, kz * 128 + 128, As, Bs, acc);
  int t = threadIdx.x, lane = t & 63, g = lane >> 4, mr = lane & 15;
  int wid = t >> 6, wr = wid >> 1, wc = wid & 1;
  int b = m0 >> 11, mchunk = (m0 >> 7) & 15;
  float wsum[4];
#pragma unroll
  for (int fn = 0; fn < 4; ++fn) {
    int col = n0 + wc * 64 + fn * 16 + mr;
    float a = 1.f / (1.f + expf(-Ap[col]));
    float la2 = log2f(a);
    float s = 0.f;
#pragma unroll
    for (int fm = 0; fm < 4; ++fm) {
      int rbase = (m0 + wr * 64 + fm * 16 + g * 4) & (L_ - 1);
#pragma unroll
      for (int q = 0; q < 4; ++q) {
        float e = (float)(2047 - (rbase + q));
        s += acc[fm][fn][q] * exp2f(e * la2);
      }
    }
    s += __shfl_xor(s, 16);
    s += __shfl_xor(s, 32);
    wsum[fn] = s;
  }
  float* red = (float*)As;
  __syncthreads();
  if (wr == 0 && g == 0) {
#pragma unroll
    for (int fn = 0; fn < 4; ++fn) red[(wc * 4 + fn) * 16 + mr] = wsum[fn];
  }
  __syncthreads();
  if (wr == 1 && g == 0) {
#pragma unroll
    for (int fn = 0; fn < 4; ++fn) {
      int col = n0 + wc * 64 + fn * 16 + mr;
      part3[(((size_t)(b * 16 + mchunk)) * 4 + kz) * 256 + col] =
          wsum[fn] + red[(wc * 4 + fn) * 16 + mr];
    }
  }
}

// ---------- tail A: hT[b][s] = a^L*(state@Wh)[s] + sum_c part3[b][c][s] ----------
// 64 blocks: 16 per batch, each owns 16 s-values.
__global__ __launch_bounds__(256) void k_tailA(const float* __restrict__ state,
                                               const float* __restrict__ Wh,
                                               const float* __restrict__ Ap,
                                               const float* __restrict__ part3,
                                               float* __restrict__ hT, int use_h0) {
  int bz = blockIdx.x;
  int b = bz >> 4, sl = (bz & 15) * 16;
  int t = threadIdx.x;
  int sx = t & 15, sy = t >> 4;   // sy in [0,16)
  __shared__ float sst[512];
  __shared__ float redh[16][17];
  __shared__ float redp[16][17];
  sst[t] = state[b * 512 + t];
  sst[t + 256] = state[b * 512 + t + 256];
  __syncthreads();
  int s = sl + sx;
  float ph = 0.f;
  if (use_h0) {
    for (int j = 0; j < 32; ++j) {
      int d = sy * 32 + j;
      ph += sst[d] * Wh[(size_t)d * 256 + s];
    }
  }
  float pp = 0.f;
#pragma unroll
  for (int c = 0; c < 4; ++c)
    pp += part3[((size_t)b * 64 + sy * 4 + c) * 256 + s];
  redh[sy][sx] = ph;
  redp[sy][sx] = pp;
  __syncthreads();
  if (t < 16) {
    int ss = sl + t;
    float h0v = 0.f, acc = 0.f;
#pragma unroll
    for (int k = 0; k < 16; ++k) { h0v += redh[k][t]; acc += redp[k][t]; }
    if (use_h0) {
      float a = 1.f / (1.f + expf(-Ap[ss]));
      acc += exp2f(2048.f * log2f(a)) * h0v;
    }
    hT[b * 256 + ss] = acc;
  }
}

// ---------- tail B: state[b][d] = sum_s hT[s] * Wout[s][d] ----------
// 64 blocks: 16 per batch, each owns 32 d-values.
__global__ __launch_bounds__(256) void k_tailB(const float* __restrict__ hT,
                                               const float* __restrict__ Wout,
                                               float* __restrict__ state) {
  int bz = blockIdx.x;
  int b = bz >> 4, dl = (bz & 15) * 32;
  int t = threadIdx.x;
  int dx = t & 31, sy = t >> 5;   // sy in [0,8)
  __shared__ float hs[256];
  __shared__ float red[8][33];
  hs[t] = hT[b * 256 + t];
  __syncthreads();
  float p = 0.f;
  for (int j = 0; j < 32; ++j) {
    int s = sy * 32 + j;
    p += hs[s] * Wout[(size_t)s * 512 + dl + dx];
  }
  red[sy][dx] = p;
  __syncthreads();
  if (t < 32) {
    float a = 0.f;
#pragma unroll
    for (int k = 0; k < 8; ++k) a += red[k][t];
    state[b * 512 + dl + t] = a;
  }
}

// ---------- flash banded attention (no-max softmax, deferred sum) ----------
__global__ __launch_bounds__(256) void k_fattn(const unsigned short* __restrict__ Qbf,
                                               const unsigned short* __restrict__ Kbf,
                                               const unsigned short* __restrict__ VbfT,
                                               unsigned short* __restrict__ attnbf) {
  __shared__ __align__(16) unsigned short Ks[64][72];
  __shared__ __align__(16) unsigned short Vt[64][72];
  __shared__ __align__(16) unsigned short Ps[4][16][72];
  int b = blockIdx.z, h = blockIdx.y, q0 = blockIdx.x * 64;
  int t = threadIdx.x;
  int lane = t & 63, wid = t >> 6;
  int g = lane >> 4, mr = lane & 15;
  const unsigned short* Qp = Qbf + ((size_t)(b * H_ + h)) * L_ * 64;
  const unsigned short* Kp = Kbf + ((size_t)(b * H_ + h)) * L_ * 64;
  const unsigned short* VpT = VbfT + ((size_t)(b * H_ + h)) * 64 * L_;
  int qbase = q0 + wid * 16;
  s16x8 qf0 = *reinterpret_cast<const s16x8*>(Qp + (size_t)(qbase + mr) * 64 + g * 8);
  s16x8 qf1 = *reinterpret_cast<const s16x8*>(Qp + (size_t)(qbase + mr) * 64 + 32 + g * 8);
  f32x4 oacc[4];
#pragma unroll
  for (int fn = 0; fn < 4; ++fn) { f32x4 zz = {0.f, 0.f, 0.f, 0.f}; oacc[fn] = zz; }
  float lsum[4] = {0.f, 0.f, 0.f, 0.f};
  int kstart = q0 - WIN_; if (kstart < 0) kstart = 0;
  int kend = q0 + 64 + WIN_; if (kend > L_) kend = L_;

  for (int kt = kstart; kt < kend; kt += 64) {
    __syncthreads();
#pragma unroll
    for (int it = 0; it < 2; ++it) {
      int chunk = t + it * 256;
      int row = chunk >> 3, c8 = (chunk & 7) * 8;
      *reinterpret_cast<s16x8*>(&Ks[row][c8]) =
          *reinterpret_cast<const s16x8*>(Kp + (size_t)(kt + row) * 64 + c8);
      *reinterpret_cast<s16x8*>(&Vt[row][c8]) =
          *reinterpret_cast<const s16x8*>(VpT + (size_t)row * L_ + kt + c8);
    }
    __syncthreads();
    f32x4 sacc[4];
#pragma unroll
    for (int n = 0; n < 4; ++n) {
      f32x4 zz = {0.f, 0.f, 0.f, 0.f};
      sacc[n] = zz;
      s16x8 kf0 = *reinterpret_cast<const s16x8*>(&Ks[n * 16 + mr][g * 8]);
      s16x8 kf1 = *reinterpret_cast<const s16x8*>(&Ks[n * 16 + mr][32 + g * 8]);
      sacc[n] = __builtin_amdgcn_mfma_f32_16x16x32_bf16(qf0, kf0, sacc[n], 0, 0, 0);
      sacc[n] = __builtin_amdgcn_mfma_f32_16x16x32_bf16(qf1, kf1, sacc[n], 0, 0, 0);
    }
    bool needmask = (kt - q0 > 192) || (q0 - kt > 192);
#pragma unroll
    for (int reg = 0; reg < 4; ++reg) {
      int q_abs = qbase + g * 4 + reg;
#pragma unroll
      for (int n = 0; n < 4; ++n) {
        float pv = exp2f(sacc[n][reg] * LOG2E_);
        if (needmask) {
          int key = kt + n * 16 + mr;
          int dd = key - q_abs; dd = dd < 0 ? -dd : dd;
          if (dd > WIN_) pv = 0.f;
        }
        lsum[reg] += pv;
        Ps[wid][g * 4 + reg][n * 16 + mr] = f2b(pv);
      }
    }
    s16x8 pa0 = *reinterpret_cast<const s16x8*>(&Ps[wid][mr][g * 8]);
    s16x8 pa1 = *reinterpret_cast<const s16x8*>(&Ps[wid][mr][32 + g * 8]);
#pragma unroll
    for (int fn = 0; fn < 4; ++fn) {
      s16x8 vf0 = *reinterpret_cast<const s16x8*>(&Vt[fn * 16 + mr][g * 8]);
      s16x8 vf1 = *reinterpret_cast<const s16x8*>(&Vt[fn * 16 + mr][32 + g * 8]);
      oacc[fn] = __builtin_amdgcn_mfma_f32_16x16x32_bf16(pa0, vf0, oacc[fn], 0, 0, 0);
      oacc[fn] = __builtin_amdgcn_mfma_f32_16x16x32_bf16(pa1, vf1, oacc[fn], 0, 0, 0);
    }
  }
#pragma unroll
  for (int reg = 0; reg < 4; ++reg) {
    float ls = lsum[reg];
#pragma unroll
    for (int off = 1; off < 16; off <<= 1) ls += __shfl_xor(ls, off);
    float inv = 1.f / ls;
    int q_abs = qbase + g * 4 + reg;
    unsigned short* dst = attnbf + ((size_t)(b * L_ + q_abs)) * 512 + h * 64;
#pragma unroll
    for (int fn = 0; fn < 4; ++fn)
      dst[fn * 16 + mr] = f2b(oacc[fn][reg] * inv);
  }
}

extern "C" void kernel_launch(void* const* d_in, const int* in_sizes, int n_in,
                              void* d_out, int out_size, void* d_ws, size_t ws_size,
                              hipStream_t stream) {
  const float* context = (const float*)d_in[0];
  const float* conv_w  = (const float*)d_in[1];
  const float* Wx      = (const float*)d_in[2];
  const float* Wh      = (const float*)d_in[3];
  const float* Wout    = (const float*)d_in[4];
  const float* Aparm   = (const float*)d_in[5];
  const float* gamma_m = (const float*)d_in[6];
  const float* beta_m  = (const float*)d_in[7];
  const float* gamma_a = (const float*)d_in[8];
  const float* beta_a  = (const float*)d_in[9];
  const float* Wqkv    = (const float*)d_in[10];
  const float* bqkv    = (const float*)d_in[11];
  const float* Wo      = (const float*)d_in[12];
  const float* bo      = (const float*)d_in[13];
  float* seqA = (float*)d_out;
  float* ws = (float*)d_ws;

  // ws layout (float units). seqB aliases Qbf+Kbf (temporally disjoint).
  float* proj = ws;                                           // 4,194,304
  float* seqB = ws + 4194304;                                 // 4,194,304 (alias Qbf/Kbf)
  unsigned short* Qbf    = (unsigned short*)(ws + 4194304);
  unsigned short* Kbf    = (unsigned short*)(ws + 6291456);
  unsigned short* VbfT   = (unsigned short*)(ws + 8388608);   // [B,H,64,L]
  unsigned short* xbf    = (unsigned short*)(ws + 10485760);
  unsigned short* sbf    = (unsigned short*)(ws + 12582912);  // seq bf16 / attn out bf16
  unsigned short* wqkvbf = (unsigned short*)(ws + 14680064);
  unsigned short* wobf   = (unsigned short*)(ws + 15073280);
  unsigned short* wxtbf  = (unsigned short*)(ws + 15204352);
  float* state = ws + 15597568;                               // 2048
  float* part3 = state + 2048;                                // 65536
  float* hT    = part3 + 65536;                               // 1024

  k_f2b<<<768, 256, 0, stream>>>(Wqkv, wqkvbf, 196608);
  k_f2b<<<256, 256, 0, stream>>>(Wo, wobf, 65536);
  k_twx<<<dim3(16, 8, 6), dim3(32, 8), 0, stream>>>(Wx, wxtbf);

  k_conv_silu<<<B_ * L_, 128, 0, stream>>>(context, conv_w, xbf);

  for (int i = 0; i < 6; ++i) {
    k_g128_u<<<dim3(64, 2, 4), 256, 0, stream>>>(xbf, wxtbf + (size_t)i * S_ * D_,
                                                 Aparm + (size_t)i * S_, part3);
    k_tailA<<<64, 256, 0, stream>>>(state, Wh + (size_t)i * D_ * S_,
                                    Aparm + (size_t)i * S_, part3, hT, i > 0 ? 1 : 0);
    k_tailB<<<64, 256, 0, stream>>>(hT, Wout + (size_t)i * S_ * D_, state);
    const float* cwn = conv_w + (size_t)(i + 1) * 3 * D_;
    switch (i) {
      case 0:
        k_lnconv<<<1024, 64, 0, stream>>>(context, state, 0, gamma_m, beta_m,
                                          seqA, xbf, cwn, nullptr);
        break;
      case 1:
        k_lnconv<<<1024, 64, 0, stream>>>(seqA, state, 0, gamma_m, beta_m,
                                          seqB, xbf, cwn, nullptr);
        break;
      case 2:
        k_lnconv<<<1024, 64, 0, stream>>>(seqB, state, 0, gamma_m, beta_m,
                                          seqA, xbf, cwn, nullptr);
        break;
      case 3:
        k_lnconv<<<1024, 64, 0, stream>>>(seqA, state, 0, gamma_m, beta_m,
                                          seqA, nullptr, nullptr, sbf);
        k_g128_qkv<<<dim3(64, 12), 256, 0, stream>>>(sbf, wqkvbf, bqkv, Qbf, Kbf, VbfT);
        k_fattn<<<dim3(32, 8, 4), 256, 0, stream>>>(Qbf, Kbf, VbfT, sbf);
        k_g128<<<dim3(64, 4), 256, 0, stream>>>(sbf, wobf, proj, bo, 512, 512);
        k_lnconv<<<1024, 64, 0, stream>>>(seqA, proj, 1, gamma_a, beta_a,
                                          seqB, xbf, cwn, nullptr);
        break;
      case 4:
        k_lnconv<<<1024, 64, 0, stream>>>(seqB, state, 0, gamma_m, beta_m,
                                          seqA, xbf, cwn, nullptr);
        break;
      case 5:
        k_lnconv<<<1024, 64, 0, stream>>>(seqA, state, 0, gamma_m, beta_m,
                                          seqA, nullptr, nullptr, nullptr);
        break;
    }
  }
}

// Round 6
// 287.703 us; speedup vs baseline: 13.9544x; 1.0417x over previous
//
#include <hip/hip_runtime.h>

#define B_ 4
#define L_ 2048
#define D_ 512
#define S_ 256
#define H_ 8
#define DH_ 64
#define WIN_ 256
#define EPS_ 1e-5f
#define LOG2E_ 1.4426950408889634f

using f32x4 = __attribute__((ext_vector_type(4))) float;
using s16x8 = __attribute__((ext_vector_type(8))) short;

__device__ __forceinline__ unsigned short f2b(float f) {
  unsigned int u = __builtin_bit_cast(unsigned int, f);
  u += 0x7FFFu + ((u >> 16) & 1u);   // RNE to bf16 (inputs finite)
  return (unsigned short)(u >> 16);
}

__device__ __forceinline__ float silu(float y) { return y / (1.f + expf(-y)); }

// async global->LDS 16B DMA: lds dest is wave-uniform base, HW adds lane*16.
__device__ __forceinline__ void gll16(const void* g, void* l) {
  __builtin_amdgcn_global_load_lds((const __attribute__((address_space(1))) void*)g,
                                   (__attribute__((address_space(3))) void*)l, 16, 0, 0);
}

// ---------- f32 -> bf16 convert (n4 = n/4) ----------
__global__ __launch_bounds__(256) void k_f2b(const float* __restrict__ in,
                                             unsigned short* __restrict__ out, int n4) {
  int i = blockIdx.x * 256 + threadIdx.x;
  if (i >= n4) return;
  float4 v = reinterpret_cast<const float4*>(in)[i];
  ushort4 o;
  o.x = f2b(v.x); o.y = f2b(v.y); o.z = f2b(v.z); o.w = f2b(v.w);
  reinterpret_cast<ushort4*>(out)[i] = o;
}

// ---------- transpose+convert Wx (NL,D,S) -> (NL,S,D) bf16 ----------
__global__ void k_twx(const float* __restrict__ wx, unsigned short* __restrict__ wxt) {
  __shared__ float tile[32][33];
  int lyr = blockIdx.z;
  int d0 = blockIdx.x * 32, s0 = blockIdx.y * 32;
  const float* src = wx + (size_t)lyr * D_ * S_;
  unsigned short* dst = wxt + (size_t)lyr * S_ * D_;
  for (int r = threadIdx.y; r < 32; r += 8)
    tile[r][threadIdx.x] = src[(size_t)(d0 + r) * S_ + s0 + threadIdx.x];
  __syncthreads();
  for (int r = threadIdx.y; r < 32; r += 8)
    dst[(size_t)(s0 + r) * D_ + d0 + threadIdx.x] = f2b(tile[threadIdx.x][r]);
}

// ---------- causal depthwise conv (k=3) + SiLU, layer-0 (reads context) ----------
__global__ __launch_bounds__(128) void k_conv_silu(const float* __restrict__ seq,
                                                   const float* __restrict__ cw,
                                                   unsigned short* __restrict__ x) {
  int bl = blockIdx.x;
  int l = bl & (L_ - 1);
  int t = threadIdx.x;
  const float4* s4 = reinterpret_cast<const float4*>(seq);
  const float4* c4 = reinterpret_cast<const float4*>(cw);
  size_t row = (size_t)bl * 128;
  float4 c0 = c4[t], c1 = c4[128 + t], c2 = c4[256 + t];
  float4 z = make_float4(0.f, 0.f, 0.f, 0.f);
  float4 s0 = (l >= 2) ? s4[row - 256 + t] : z;
  float4 s1 = (l >= 1) ? s4[row - 128 + t] : z;
  float4 s2 = s4[row + t];
  float y0 = c0.x * s0.x + c1.x * s1.x + c2.x * s2.x;
  float y1 = c0.y * s0.y + c1.y * s1.y + c2.y * s2.y;
  float y2 = c0.z * s0.z + c1.z * s1.z + c2.z * s2.z;
  float y3 = c0.w * s0.w + c1.w * s1.w + c2.w * s2.w;
  ushort4 o;
  o.x = f2b(silu(y0)); o.y = f2b(silu(y1)); o.z = f2b(silu(y2)); o.w = f2b(silu(y3));
  reinterpret_cast<ushort4*>(x)[row + t] = o;
}

// ---------- fused LayerNorm(seqIn + add) -> seqOut [+bf16 mirror] [+conv(k=3)+SiLU -> xbf] ----------
__global__ __launch_bounds__(64) void k_lnconv(const float* __restrict__ seqIn,
                                               const float* __restrict__ add, int addfull,
                                               const float* __restrict__ gamma,
                                               const float* __restrict__ beta,
                                               float* __restrict__ seqOut,
                                               unsigned short* __restrict__ xbf,
                                               const float* __restrict__ cw,
                                               unsigned short* __restrict__ sbf) {
  int t = threadIdx.x;
  int r0 = blockIdx.x * 8;
  int b = r0 >> 11, l0 = r0 & (L_ - 1);
  bool hasconv = (cw != nullptr);
  const float4* in4 = reinterpret_cast<const float4*>(seqIn);
  const float4* ad4 = reinterpret_cast<const float4*>(add);
  float4* out4 = reinterpret_cast<float4*>(seqOut);
  float4 g0 = reinterpret_cast<const float4*>(gamma)[2 * t];
  float4 g1 = reinterpret_cast<const float4*>(gamma)[2 * t + 1];
  float4 be0 = reinterpret_cast<const float4*>(beta)[2 * t];
  float4 be1 = reinterpret_cast<const float4*>(beta)[2 * t + 1];
  float4 av0, av1;
  if (!addfull) { av0 = ad4[b * 128 + 2 * t]; av1 = ad4[b * 128 + 2 * t + 1]; }
  float4 c0a, c0b, c1a, c1b, c2a, c2b;
  if (hasconv) {
    const float4* c4 = reinterpret_cast<const float4*>(cw);
    c0a = c4[2 * t]; c0b = c4[2 * t + 1];
    c1a = c4[128 + 2 * t]; c1b = c4[128 + 2 * t + 1];
    c2a = c4[256 + 2 * t]; c2b = c4[256 + 2 * t + 1];
  }
  float4 z = make_float4(0.f, 0.f, 0.f, 0.f);
  float4 m2a = z, m2b = z, m1a = z, m1b = z;
  int nrows = hasconv ? 10 : 8;
  int lstart = hasconv ? l0 - 2 : l0;
  for (int j = 0; j < nrows; ++j) {
    int l = lstart + j;
    float4 oa = z, ob = z;
    if (l >= 0) {
      size_t r4 = ((size_t)(b * L_ + l)) * 128;
      float4 v0 = in4[r4 + 2 * t], v1 = in4[r4 + 2 * t + 1];
      float4 a0, a1;
      if (addfull) { a0 = ad4[r4 + 2 * t]; a1 = ad4[r4 + 2 * t + 1]; }
      else { a0 = av0; a1 = av1; }
      v0.x += a0.x; v0.y += a0.y; v0.z += a0.z; v0.w += a0.w;
      v1.x += a1.x; v1.y += a1.y; v1.z += a1.z; v1.w += a1.w;
      float sx = v0.x + v0.y + v0.z + v0.w + v1.x + v1.y + v1.z + v1.w;
      float sq = v0.x * v0.x + v0.y * v0.y + v0.z * v0.z + v0.w * v0.w +
                 v1.x * v1.x + v1.y * v1.y + v1.z * v1.z + v1.w * v1.w;
#pragma unroll
      for (int off = 1; off < 64; off <<= 1) {
        sx += __shfl_xor(sx, off);
        sq += __shfl_xor(sq, off);
      }
      float mu = sx * (1.f / D_);
      float var = sq * (1.f / D_) - mu * mu;
      float rstd = rsqrtf(var + EPS_);
      oa.x = (v0.x - mu) * rstd * g0.x + be0.x;
      oa.y = (v0.y - mu) * rstd * g0.y + be0.y;
      oa.z = (v0.z - mu) * rstd * g0.z + be0.z;
      oa.w = (v0.w - mu) * rstd * g0.w + be0.w;
      ob.x = (v1.x - mu) * rstd * g1.x + be1.x;
      ob.y = (v1.y - mu) * rstd * g1.y + be1.y;
      ob.z = (v1.z - mu) * rstd * g1.z + be1.z;
      ob.w = (v1.w - mu) * rstd * g1.w + be1.w;
      if (l >= l0) {
        out4[r4 + 2 * t] = oa;
        out4[r4 + 2 * t + 1] = ob;
        if (sbf) {
          s16x8 sb;
          sb[0] = (short)f2b(oa.x); sb[1] = (short)f2b(oa.y);
          sb[2] = (short)f2b(oa.z); sb[3] = (short)f2b(oa.w);
          sb[4] = (short)f2b(ob.x); sb[5] = (short)f2b(ob.y);
          sb[6] = (short)f2b(ob.z); sb[7] = (short)f2b(ob.w);
          *reinterpret_cast<s16x8*>(sbf + ((size_t)(b * L_ + l)) * 512 + t * 8) = sb;
        }
      }
    }
    if (hasconv && j >= 2) {
      float y0 = c0a.x * m2a.x + c1a.x * m1a.x + c2a.x * oa.x;
      float y1 = c0a.y * m2a.y + c1a.y * m1a.y + c2a.y * oa.y;
      float y2 = c0a.z * m2a.z + c1a.z * m1a.z + c2a.z * oa.z;
      float y3 = c0a.w * m2a.w + c1a.w * m1a.w + c2a.w * oa.w;
      float y4 = c0b.x * m2b.x + c1b.x * m1b.x + c2b.x * ob.x;
      float y5 = c0b.y * m2b.y + c1b.y * m1b.y + c2b.y * ob.y;
      float y6 = c0b.z * m2b.z + c1b.z * m1b.z + c2b.z * ob.z;
      float y7 = c0b.w * m2b.w + c1b.w * m1b.w + c2b.w * ob.w;
      s16x8 xo;
      xo[0] = (short)f2b(silu(y0)); xo[1] = (short)f2b(silu(y1));
      xo[2] = (short)f2b(silu(y2)); xo[3] = (short)f2b(silu(y3));
      xo[4] = (short)f2b(silu(y4)); xo[5] = (short)f2b(silu(y5));
      xo[6] = (short)f2b(silu(y6)); xo[7] = (short)f2b(silu(y7));
      *reinterpret_cast<s16x8*>(xbf + ((size_t)(b * L_ + l)) * 512 + t * 8) = xo;
    }
    m2a = m1a; m2b = m1b; m1a = oa; m1b = ob;
  }
}

// ---------- 128x128 bf16 MFMA GEMM core: 2-phase double-buffered stage-ahead ----------
// As/Bs are each 8192 shorts (two 4096-short buffers). Per K-step: issue next-tile
// DMA FIRST, then ds_read+MFMA current tile, then one barrier (its vmcnt(0) drain
// lands after compute has covered the prefetch latency). T3 minimum-2-phase recipe.
__device__ __forceinline__ void g128_core(const unsigned short* __restrict__ A,
                                          const unsigned short* __restrict__ Bt,
                                          int K, int m0, int n0, int k_lo, int k_hi,
                                          unsigned short* As, unsigned short* Bs,
                                          f32x4 (&acc)[4][4]) {
  int t = threadIdx.x;
  int lane = t & 63;
  int g = lane >> 4, mr = lane & 15;
  int wid = t >> 6, wr = wid >> 1, wc = wid & 1;
#pragma unroll
  for (int i = 0; i < 4; ++i)
#pragma unroll
    for (int j = 0; j < 4; ++j) { f32x4 z = {0.f, 0.f, 0.f, 0.f}; acc[i][j] = z; }
  int r0 = t >> 2, p = (t & 3) * 8;
  const unsigned short* ag0 = A + (size_t)(m0 + r0) * K + p;
  const unsigned short* ag1 = ag0 + (size_t)64 * K;
  const unsigned short* bg0 = Bt + (size_t)(n0 + r0) * K + p;
  const unsigned short* bg1 = bg0 + (size_t)64 * K;
  int woff = wid * 512;
  // prologue: stage first tile into buf0, drain
  gll16(ag0 + k_lo, As + woff);
  gll16(ag1 + k_lo, As + 2048 + woff);
  gll16(bg0 + k_lo, Bs + woff);
  gll16(bg1 + k_lo, Bs + 2048 + woff);
  __syncthreads();
  int cur = 0;
  for (int k0 = k_lo; k0 < k_hi; k0 += 32) {
    if (k0 + 32 < k_hi) {
      int nb = (cur ^ 1) * 4096;
      gll16(ag0 + k0 + 32, As + nb + woff);
      gll16(ag1 + k0 + 32, As + nb + 2048 + woff);
      gll16(bg0 + k0 + 32, Bs + nb + woff);
      gll16(bg1 + k0 + 32, Bs + nb + 2048 + woff);
    }
    const unsigned short* Ar = As + cur * 4096;
    const unsigned short* Br = Bs + cur * 4096;
    s16x8 af[4], bf[4];
#pragma unroll
    for (int fm = 0; fm < 4; ++fm)
      af[fm] = *reinterpret_cast<const s16x8*>(Ar + (size_t)(wr * 64 + fm * 16 + mr) * 32 + g * 8);
#pragma unroll
    for (int fn = 0; fn < 4; ++fn)
      bf[fn] = *reinterpret_cast<const s16x8*>(Br + (size_t)(wc * 64 + fn * 16 + mr) * 32 + g * 8);
#pragma unroll
    for (int fm = 0; fm < 4; ++fm)
#pragma unroll
      for (int fn = 0; fn < 4; ++fn)
        acc[fm][fn] = __builtin_amdgcn_mfma_f32_16x16x32_bf16(af[fm], bf[fn], acc[fm][fn], 0, 0, 0);
    __syncthreads();   // drains vmcnt(0): next tile ready; all reads of cur done
    cur ^= 1;
  }
}

// ---------- plain C = A*Bt^T (+bias), f32 out ----------
__global__ __launch_bounds__(256) void k_g128(const unsigned short* __restrict__ A,
                                              const unsigned short* __restrict__ Bt,
                                              float* __restrict__ C,
                                              const float* __restrict__ bias,
                                              int N, int K) {
  __shared__ __align__(16) unsigned short As[8192], Bs[8192];
  int m0 = blockIdx.x * 128, n0 = blockIdx.y * 128;
  f32x4 acc[4][4];
  g128_core(A, Bt, K, m0, n0, 0, K, As, Bs, acc);
  int t = threadIdx.x, lane = t & 63, g = lane >> 4, mr = lane & 15;
  int wid = t >> 6, wr = wid >> 1, wc = wid & 1;
#pragma unroll
  for (int fm = 0; fm < 4; ++fm)
#pragma unroll
    for (int fn = 0; fn < 4; ++fn) {
      int row = m0 + wr * 64 + fm * 16 + g * 4;
      int col = n0 + wc * 64 + fn * 16 + mr;
      float badd = bias ? bias[col] : 0.f;
#pragma unroll
      for (int q = 0; q < 4; ++q)
        C[(size_t)(row + q) * N + col] = acc[fm][fn][q] + badd;
    }
}

// ---------- QKV GEMM: Q(scaled)/K -> [B,H,L,64]; V -> transposed [B,H,64,L] ----------
__global__ __launch_bounds__(256) void k_g128_qkv(const unsigned short* __restrict__ A,
                                                  const unsigned short* __restrict__ Bt,
                                                  const float* __restrict__ bias,
                                                  unsigned short* __restrict__ Qbf,
                                                  unsigned short* __restrict__ Kbf,
                                                  unsigned short* __restrict__ VbfT) {
  __shared__ __align__(16) unsigned short sm[16384];
  int m0 = blockIdx.x * 128, n0 = blockIdx.y * 128;
  f32x4 acc[4][4];
  g128_core(A, Bt, 512, m0, n0, 0, 512, sm, sm + 8192, acc);
  int t = threadIdx.x, lane = t & 63, g = lane >> 4, mr = lane & 15;
  int wid = t >> 6, wr = wid >> 1, wc = wid & 1;
  int b = m0 >> 11, l0 = m0 & (L_ - 1);
  if (n0 < 1024) {
#pragma unroll
    for (int fm = 0; fm < 4; ++fm)
#pragma unroll
      for (int fn = 0; fn < 4; ++fn) {
        int row0 = m0 + wr * 64 + fm * 16 + g * 4;
        int col = n0 + wc * 64 + fn * 16 + mr;
        int sec = col >> 9;           // 0=Q 1=K
        int hh = (col >> 6) & 7;
        int dh = col & 63;
        float badd = bias[col];
        float scale = (sec == 0) ? 0.125f : 1.f;
        unsigned short* dstbase = (sec == 0) ? Qbf : Kbf;
#pragma unroll
        for (int q = 0; q < 4; ++q) {
          int row = row0 + q;
          int bb = row >> 11, l = row & (L_ - 1);
          dstbase[(((size_t)(bb * H_ + hh)) * L_ + l) * 64 + dh] =
              f2b((acc[fm][fn][q] + badd) * scale);
        }
      }
  } else {
#pragma unroll
    for (int chalf = 0; chalf < 2; ++chalf) {
      __syncthreads();
      if (wc == chalf) {
#pragma unroll
        for (int fm = 0; fm < 4; ++fm)
#pragma unroll
          for (int fn = 0; fn < 4; ++fn) {
            int col = n0 + wc * 64 + fn * 16 + mr;
            float badd = bias[col];
            int col_local = fn * 16 + mr;
            int row_local = wr * 64 + fm * 16 + g * 4;
            ushort4 pk;
            pk.x = f2b(acc[fm][fn][0] + badd);
            pk.y = f2b(acc[fm][fn][1] + badd);
            pk.z = f2b(acc[fm][fn][2] + badd);
            pk.w = f2b(acc[fm][fn][3] + badd);
            *reinterpret_cast<ushort4*>(&sm[col_local * 128 + row_local]) = pk;
          }
      }
      __syncthreads();
      int c = t >> 2, lp = (t & 3) * 32;
      int h = ((n0 - 1024) >> 6) + chalf;
      unsigned short* dst = VbfT + (((size_t)(b * H_ + h)) * 64 + c) * L_ + l0 + lp;
#pragma unroll
      for (int u = 0; u < 4; ++u)
        *reinterpret_cast<s16x8*>(dst + u * 8) =
            *reinterpret_cast<const s16x8*>(&sm[c * 128 + lp + u * 8]);
    }
  }
}

// ---------- u GEMM (split-K over blockIdx.z) with fused decay-weighted row reduction ----------
__global__ __launch_bounds__(256) void k_g128_u(const unsigned short* __restrict__ A,
                                                const unsigned short* __restrict__ Bt,
                                                const float* __restrict__ Ap,
                                                float* __restrict__ part3) {
  __shared__ __align__(16) unsigned short As[8192], Bs[8192];
  int m0 = blockIdx.x * 128, n0 = blockIdx.y * 128;
  int kz = blockIdx.z;
  f32x4 acc[4][4];
  g128_core(A, Bt, 512, m0, n0, kz * 128, kz * 128 + 128, As, Bs, acc);
  int t = threadIdx.x, lane = t & 63, g = lane >> 4, mr = lane & 15;
  int wid = t >> 6, wr = wid >> 1, wc = wid & 1;
  int b = m0 >> 11, mchunk = (m0 >> 7) & 15;
  float wsum[4];
#pragma unroll
  for (int fn = 0; fn < 4; ++fn) {
    int col = n0 + wc * 64 + fn * 16 + mr;
    float a = 1.f / (1.f + expf(-Ap[col]));
    float la2 = log2f(a);
    float s = 0.f;
#pragma unroll
    for (int fm = 0; fm < 4; ++fm) {
      int rbase = (m0 + wr * 64 + fm * 16 + g * 4) & (L_ - 1);
#pragma unroll
      for (int q = 0; q < 4; ++q) {
        float e = (float)(2047 - (rbase + q));
        s += acc[fm][fn][q] * exp2f(e * la2);
      }
    }
    s += __shfl_xor(s, 16);
    s += __shfl_xor(s, 32);
    wsum[fn] = s;
  }
  float* red = (float*)As;
  __syncthreads();
  if (wr == 0 && g == 0) {
#pragma unroll
    for (int fn = 0; fn < 4; ++fn) red[(wc * 4 + fn) * 16 + mr] = wsum[fn];
  }
  __syncthreads();
  if (wr == 1 && g == 0) {
#pragma unroll
    for (int fn = 0; fn < 4; ++fn) {
      int col = n0 + wc * 64 + fn * 16 + mr;
      part3[(((size_t)(b * 16 + mchunk)) * 4 + kz) * 256 + col] =
          wsum[fn] + red[(wc * 4 + fn) * 16 + mr];
    }
  }
}

// ---------- tail A: hT[b][s] = a^L*(state@Wh)[s] + sum_c part3[b][c][s] ----------
__global__ __launch_bounds__(256) void k_tailA(const float* __restrict__ state,
                                               const float* __restrict__ Wh,
                                               const float* __restrict__ Ap,
                                               const float* __restrict__ part3,
                                               float* __restrict__ hT, int use_h0) {
  int bz = blockIdx.x;
  int b = bz >> 4, sl = (bz & 15) * 16;
  int t = threadIdx.x;
  int sx = t & 15, sy = t >> 4;   // sy in [0,16)
  __shared__ float sst[512];
  __shared__ float redh[16][17];
  __shared__ float redp[16][17];
  sst[t] = state[b * 512 + t];
  sst[t + 256] = state[b * 512 + t + 256];
  __syncthreads();
  int s = sl + sx;
  float ph = 0.f;
  if (use_h0) {
    for (int j = 0; j < 32; ++j) {
      int d = sy * 32 + j;
      ph += sst[d] * Wh[(size_t)d * 256 + s];
    }
  }
  float pp = 0.f;
#pragma unroll
  for (int c = 0; c < 4; ++c)
    pp += part3[((size_t)b * 64 + sy * 4 + c) * 256 + s];
  redh[sy][sx] = ph;
  redp[sy][sx] = pp;
  __syncthreads();
  if (t < 16) {
    int ss = sl + t;
    float h0v = 0.f, acc = 0.f;
#pragma unroll
    for (int k = 0; k < 16; ++k) { h0v += redh[k][t]; acc += redp[k][t]; }
    if (use_h0) {
      float a = 1.f / (1.f + expf(-Ap[ss]));
      acc += exp2f(2048.f * log2f(a)) * h0v;
    }
    hT[b * 256 + ss] = acc;
  }
}

// ---------- tail B: state[b][d] = sum_s hT[s] * Wout[s][d] ----------
__global__ __launch_bounds__(256) void k_tailB(const float* __restrict__ hT,
                                               const float* __restrict__ Wout,
                                               float* __restrict__ state) {
  int bz = blockIdx.x;
  int b = bz >> 4, dl = (bz & 15) * 32;
  int t = threadIdx.x;
  int dx = t & 31, sy = t >> 5;   // sy in [0,8)
  __shared__ float hs[256];
  __shared__ float red[8][33];
  hs[t] = hT[b * 256 + t];
  __syncthreads();
  float p = 0.f;
  for (int j = 0; j < 32; ++j) {
    int s = sy * 32 + j;
    p += hs[s] * Wout[(size_t)s * 512 + dl + dx];
  }
  red[sy][dx] = p;
  __syncthreads();
  if (t < 32) {
    float a = 0.f;
#pragma unroll
    for (int k = 0; k < 8; ++k) a += red[k][t];
    state[b * 512 + dl + t] = a;
  }
}

// ---------- flash banded attention (no-max softmax, deferred sum) ----------
__global__ __launch_bounds__(256) void k_fattn(const unsigned short* __restrict__ Qbf,
                                               const unsigned short* __restrict__ Kbf,
                                               const unsigned short* __restrict__ VbfT,
                                               unsigned short* __restrict__ attnbf) {
  __shared__ __align__(16) unsigned short Ks[64][72];
  __shared__ __align__(16) unsigned short Vt[64][72];
  __shared__ __align__(16) unsigned short Ps[4][16][72];
  int b = blockIdx.z, h = blockIdx.y, q0 = blockIdx.x * 64;
  int t = threadIdx.x;
  int lane = t & 63, wid = t >> 6;
  int g = lane >> 4, mr = lane & 15;
  const unsigned short* Qp = Qbf + ((size_t)(b * H_ + h)) * L_ * 64;
  const unsigned short* Kp = Kbf + ((size_t)(b * H_ + h)) * L_ * 64;
  const unsigned short* VpT = VbfT + ((size_t)(b * H_ + h)) * 64 * L_;
  int qbase = q0 + wid * 16;
  s16x8 qf0 = *reinterpret_cast<const s16x8*>(Qp + (size_t)(qbase + mr) * 64 + g * 8);
  s16x8 qf1 = *reinterpret_cast<const s16x8*>(Qp + (size_t)(qbase + mr) * 64 + 32 + g * 8);
  f32x4 oacc[4];
#pragma unroll
  for (int fn = 0; fn < 4; ++fn) { f32x4 zz = {0.f, 0.f, 0.f, 0.f}; oacc[fn] = zz; }
  float lsum[4] = {0.f, 0.f, 0.f, 0.f};
  int kstart = q0 - WIN_; if (kstart < 0) kstart = 0;
  int kend = q0 + 64 + WIN_; if (kend > L_) kend = L_;

  for (int kt = kstart; kt < kend; kt += 64) {
    __syncthreads();
#pragma unroll
    for (int it = 0; it < 2; ++it) {
      int chunk = t + it * 256;
      int row = chunk >> 3, c8 = (chunk & 7) * 8;
      *reinterpret_cast<s16x8*>(&Ks[row][c8]) =
          *reinterpret_cast<const s16x8*>(Kp + (size_t)(kt + row) * 64 + c8);
      *reinterpret_cast<s16x8*>(&Vt[row][c8]) =
          *reinterpret_cast<const s16x8*>(VpT + (size_t)row * L_ + kt + c8);
    }
    __syncthreads();
    f32x4 sacc[4];
#pragma unroll
    for (int n = 0; n < 4; ++n) {
      f32x4 zz = {0.f, 0.f, 0.f, 0.f};
      sacc[n] = zz;
      s16x8 kf0 = *reinterpret_cast<const s16x8*>(&Ks[n * 16 + mr][g * 8]);
      s16x8 kf1 = *reinterpret_cast<const s16x8*>(&Ks[n * 16 + mr][32 + g * 8]);
      sacc[n] = __builtin_amdgcn_mfma_f32_16x16x32_bf16(qf0, kf0, sacc[n], 0, 0, 0);
      sacc[n] = __builtin_amdgcn_mfma_f32_16x16x32_bf16(qf1, kf1, sacc[n], 0, 0, 0);
    }
    bool needmask = (kt - q0 > 192) || (q0 - kt > 192);
#pragma unroll
    for (int reg = 0; reg < 4; ++reg) {
      int q_abs = qbase + g * 4 + reg;
#pragma unroll
      for (int n = 0; n < 4; ++n) {
        float pv = exp2f(sacc[n][reg] * LOG2E_);
        if (needmask) {
          int key = kt + n * 16 + mr;
          int dd = key - q_abs; dd = dd < 0 ? -dd : dd;
          if (dd > WIN_) pv = 0.f;
        }
        lsum[reg] += pv;
        Ps[wid][g * 4 + reg][n * 16 + mr] = f2b(pv);
      }
    }
    s16x8 pa0 = *reinterpret_cast<const s16x8*>(&Ps[wid][mr][g * 8]);
    s16x8 pa1 = *reinterpret_cast<const s16x8*>(&Ps[wid][mr][32 + g * 8]);
#pragma unroll
    for (int fn = 0; fn < 4; ++fn) {
      s16x8 vf0 = *reinterpret_cast<const s16x8*>(&Vt[fn * 16 + mr][g * 8]);
      s16x8 vf1 = *reinterpret_cast<const s16x8*>(&Vt[fn * 16 + mr][32 + g * 8]);
      oacc[fn] = __builtin_amdgcn_mfma_f32_16x16x32_bf16(pa0, vf0, oacc[fn], 0, 0, 0);
      oacc[fn] = __builtin_amdgcn_mfma_f32_16x16x32_bf16(pa1, vf1, oacc[fn], 0, 0, 0);
    }
  }
#pragma unroll
  for (int reg = 0; reg < 4; ++reg) {
    float ls = lsum[reg];
#pragma unroll
    for (int off = 1; off < 16; off <<= 1) ls += __shfl_xor(ls, off);
    float inv = 1.f / ls;
    int q_abs = qbase + g * 4 + reg;
    unsigned short* dst = attnbf + ((size_t)(b * L_ + q_abs)) * 512 + h * 64;
#pragma unroll
    for (int fn = 0; fn < 4; ++fn)
      dst[fn * 16 + mr] = f2b(oacc[fn][reg] * inv);
  }
}

extern "C" void kernel_launch(void* const* d_in, const int* in_sizes, int n_in,
                              void* d_out, int out_size, void* d_ws, size_t ws_size,
                              hipStream_t stream) {
  const float* context = (const float*)d_in[0];
  const float* conv_w  = (const float*)d_in[1];
  const float* Wx      = (const float*)d_in[2];
  const float* Wh      = (const float*)d_in[3];
  const float* Wout    = (const float*)d_in[4];
  const float* Aparm   = (const float*)d_in[5];
  const float* gamma_m = (const float*)d_in[6];
  const float* beta_m  = (const float*)d_in[7];
  const float* gamma_a = (const float*)d_in[8];
  const float* beta_a  = (const float*)d_in[9];
  const float* Wqkv    = (const float*)d_in[10];
  const float* bqkv    = (const float*)d_in[11];
  const float* Wo      = (const float*)d_in[12];
  const float* bo      = (const float*)d_in[13];
  float* seqA = (float*)d_out;
  float* ws = (float*)d_ws;

  // ws layout (float units). seqB aliases Qbf+Kbf (temporally disjoint).
  float* proj = ws;                                           // 4,194,304
  float* seqB = ws + 4194304;                                 // 4,194,304 (alias Qbf/Kbf)
  unsigned short* Qbf    = (unsigned short*)(ws + 4194304);
  unsigned short* Kbf    = (unsigned short*)(ws + 6291456);
  unsigned short* VbfT   = (unsigned short*)(ws + 8388608);   // [B,H,64,L]
  unsigned short* xbf    = (unsigned short*)(ws + 10485760);
  unsigned short* sbf    = (unsigned short*)(ws + 12582912);  // seq bf16 / attn out bf16
  unsigned short* wqkvbf = (unsigned short*)(ws + 14680064);
  unsigned short* wobf   = (unsigned short*)(ws + 15073280);
  unsigned short* wxtbf  = (unsigned short*)(ws + 15204352);
  float* state = ws + 15597568;                               // 2048
  float* part3 = state + 2048;                                // 65536
  float* hT    = part3 + 65536;                               // 1024

  k_f2b<<<768, 256, 0, stream>>>(Wqkv, wqkvbf, 196608);
  k_f2b<<<256, 256, 0, stream>>>(Wo, wobf, 65536);
  k_twx<<<dim3(16, 8, 6), dim3(32, 8), 0, stream>>>(Wx, wxtbf);

  k_conv_silu<<<B_ * L_, 128, 0, stream>>>(context, conv_w, xbf);

  for (int i = 0; i < 6; ++i) {
    k_g128_u<<<dim3(64, 2, 4), 256, 0, stream>>>(xbf, wxtbf + (size_t)i * S_ * D_,
                                                 Aparm + (size_t)i * S_, part3);
    k_tailA<<<64, 256, 0, stream>>>(state, Wh + (size_t)i * D_ * S_,
                                    Aparm + (size_t)i * S_, part3, hT, i > 0 ? 1 : 0);
    k_tailB<<<64, 256, 0, stream>>>(hT, Wout + (size_t)i * S_ * D_, state);
    const float* cwn = conv_w + (size_t)(i + 1) * 3 * D_;
    switch (i) {
      case 0:
        k_lnconv<<<1024, 64, 0, stream>>>(context, state, 0, gamma_m, beta_m,
                                          seqA, xbf, cwn, nullptr);
        break;
      case 1:
        k_lnconv<<<1024, 64, 0, stream>>>(seqA, state, 0, gamma_m, beta_m,
                                          seqB, xbf, cwn, nullptr);
        break;
      case 2:
        k_lnconv<<<1024, 64, 0, stream>>>(seqB, state, 0, gamma_m, beta_m,
                                          seqA, xbf, cwn, nullptr);
        break;
      case 3:
        k_lnconv<<<1024, 64, 0, stream>>>(seqA, state, 0, gamma_m, beta_m,
                                          seqA, nullptr, nullptr, sbf);
        k_g128_qkv<<<dim3(64, 12), 256, 0, stream>>>(sbf, wqkvbf, bqkv, Qbf, Kbf, VbfT);
        k_fattn<<<dim3(32, 8, 4), 256, 0, stream>>>(Qbf, Kbf, VbfT, sbf);
        k_g128<<<dim3(64, 4), 256, 0, stream>>>(sbf, wobf, proj, bo, 512, 512);
        k_lnconv<<<1024, 64, 0, stream>>>(seqA, proj, 1, gamma_a, beta_a,
                                          seqB, xbf, cwn, nullptr);
        break;
      case 4:
        k_lnconv<<<1024, 64, 0, stream>>>(seqB, state, 0, gamma_m, beta_m,
                                          seqA, xbf, cwn, nullptr);
        break;
      case 5:
        k_lnconv<<<1024, 64, 0, stream>>>(seqA, state, 0, gamma_m, beta_m,
                                          seqA, nullptr, nullptr, nullptr);
        break;
    }
  }
}